// Round 9
// baseline (526.450 us; speedup 1.0000x reference)
//
#include <hip/hip_runtime.h>
#include <hip/hip_bf16.h>

// dims
#define BB 4
#define LL 4096
#define DM 1024
#define HH 16
#define DHD 64
#define KB 8
#define BL 16384  // BB*LL
#define FLAGCAP 131072

typedef __attribute__((ext_vector_type(8))) short short8;
typedef __attribute__((ext_vector_type(4))) short short4v;
typedef __attribute__((ext_vector_type(4))) float float4v;

#define MFMA16(A, Bx, C) __builtin_amdgcn_mfma_f32_16x16x32_bf16(A, Bx, C, 0, 0, 0)

static __device__ __forceinline__ short bf16s(float f) {
  __hip_bfloat16 h = __float2bfloat16(f);
  return *reinterpret_cast<short*>(&h);
}
static __device__ __forceinline__ float b2f(short s) {
  __hip_bfloat16 h = *reinterpret_cast<__hip_bfloat16*>(&s);
  return __bfloat162float(h);
}
// async global->LDS DMA, 16B/lane; LDS dest = uniform base + lane*16
static __device__ __forceinline__ void gl16(const void* g, void* l) {
  __builtin_amdgcn_global_load_lds(
      (const __attribute__((address_space(1))) void*)g,
      (__attribute__((address_space(3))) void*)l, 16, 0, 0);
}

// ---------------------------------------------------------------------------
// prep_wt: transpose wq/wk/wv/wo ([k][n] fp32) -> [n][k] bf16
// ---------------------------------------------------------------------------
__global__ __launch_bounds__(256) void prep_wt(const float* __restrict__ wq,
                                               const float* __restrict__ wk,
                                               const float* __restrict__ wv,
                                               const float* __restrict__ wo,
                                               __hip_bfloat16* __restrict__ wt_qkv,
                                               __hip_bfloat16* __restrict__ wt_o) {
  int blk = blockIdx.x;
  int s = blk >> 8;
  int rem = blk & 255;
  int k0 = (rem >> 4) * 64;
  int n0 = (rem & 15) * 64;
  const float* src = (s == 0) ? wq : (s == 1) ? wk : (s == 2) ? wv : wo;
  __hip_bfloat16* dst = (s < 3) ? (wt_qkv + (size_t)s * 1024 * 1024) : wt_o;
  __shared__ float ls[64][65];
  int t = threadIdx.x;
#pragma unroll
  for (int p = 0; p < 4; ++p) {
    int sid = p * 256 + t;
    int r = sid >> 4, c4 = sid & 15;
    float4 v = *reinterpret_cast<const float4*>(src + (size_t)(k0 + r) * 1024 + n0 + c4 * 4);
    ls[r][c4 * 4 + 0] = v.x; ls[r][c4 * 4 + 1] = v.y;
    ls[r][c4 * 4 + 2] = v.z; ls[r][c4 * 4 + 3] = v.w;
  }
  __syncthreads();
#pragma unroll
  for (int p = 0; p < 4; ++p) {
    int sid = p * 256 + t;
    int n = sid >> 4, kq = sid & 15;
    short4v pk;
#pragma unroll
    for (int j = 0; j < 4; ++j) pk[j] = bf16s(ls[kq * 4 + j][n]);
    *reinterpret_cast<short4v*>(dst + (size_t)(n0 + n) * 1024 + k0 + kq * 4) = pk;
  }
}

// ---------------------------------------------------------------------------
// prep_wsc: fused score weights. wscg[g][d][kk] fp64, bsc[col] fp64,
// whb/wmb [col][d] bf16 hi/mid split. grid 256, 256 thr.
// ---------------------------------------------------------------------------
__global__ __launch_bounds__(256) void prep_wsc(const float* __restrict__ wq,
                                                const float* __restrict__ wk,
                                                const float* __restrict__ wsh,
                                                const float* __restrict__ wqs,
                                                const float* __restrict__ wks,
                                                const float* __restrict__ bq,
                                                const float* __restrict__ bk,
                                                double* __restrict__ wscg,
                                                double* __restrict__ bsc,
                                                __hip_bfloat16* __restrict__ whb,
                                                __hip_bfloat16* __restrict__ wmb) {
  int col = blockIdx.x;
  int side = col >> 7, h = (col >> 3) & 15, kk = col & 7;
  int g = side * 16 + h;
  const float* w = side ? wk : wq;
  const float* wscore = side ? wks : wqs;
  __shared__ double mix[64];
  int t = threadIdx.x;
  if (t < 64)
    mix[t] = 0.9 * (double)wsh[(h * 64 + t) * 8 + kk] +
             0.1 * (double)wscore[(h * 64 + t) * 8 + kk];
  __syncthreads();
#pragma unroll
  for (int p = 0; p < 4; ++p) {
    int d = p * 256 + t;
    double acc = 0.0;
    const float* wr = w + (size_t)d * 1024 + h * 64;
#pragma unroll
    for (int j = 0; j < 64; ++j) acc += (double)wr[j] * mix[j];
    wscg[((size_t)g * 1024 + d) * 8 + kk] = acc;
    short hi = bf16s((float)acc);
    short mid = bf16s((float)(acc - (double)b2f(hi)));
    *reinterpret_cast<short*>(whb + (size_t)col * 1024 + d) = hi;
    *reinterpret_cast<short*>(wmb + (size_t)col * 1024 + d) = mid;
  }
  if (t == 0) {
    const float* br = (side ? bk : bq) + h * 64;
    double acc = 0.0;
    for (int j = 0; j < 64; ++j) acc += (double)br[j] * mix[j];
    bsc[col] = acc;
  }
}

// ---------------------------------------------------------------------------
// score_gemm R9: S = x*Wsc + b via bf16-split MFMA (xh*wh + xh*wm + xl*wh).
// MERGED y-grid: one 512-thr block (8 waves, 2x4 layout) handles the full
// 64x256 output strip. vs R6 (grid (256,2), 256 thr, 80KB LDS = 1 block/CU
// boundary case, 2 serial rounds, x loaded+converted TWICE):
//  - x loaded/converted once; xb store unguarded.
//  - B = all 256 cols, dbuf 2x64KB; LDS total 144KB (1 block/CU by design,
//    8 waves). grid 256 = one block per CU, single round, no tail.
//  - No explicit vmcnt: the convert's implicit wait on x (youngest VM ops)
//    drains each wave's older B(t) DMAs before barrier1; barrier2 then
//    publishes B(t) + A ds_writes (lgkmcnt(0)). WAR on A single-buffer and
//    B dbuf guaranteed by barrier1 (all waves past compute(t-1)).
// Accumulation order per output element unchanged -> bit-identical S.
// Fused xcvt + bucket epilogue as before (n0 = 0; block covers all 32 g).
// ---------------------------------------------------------------------------
__global__ __launch_bounds__(512) void score_gemm(const float* __restrict__ x,
                                                  const __hip_bfloat16* __restrict__ whb,
                                                  const __hip_bfloat16* __restrict__ wmb,
                                                  const double* __restrict__ bsc,
                                                  __hip_bfloat16* __restrict__ xb,
                                                  int* __restrict__ bid,
                                                  float* __restrict__ psumg,
                                                  int* __restrict__ flagcnt,
                                                  int* __restrict__ list) {
  __shared__ char sm[147456];  // xh 8K | xl 8K | Bbuf0 (wh32K|wm32K) | Bbuf1 (wh32K|wm32K)
  int t = threadIdx.x;
  int m0 = blockIdx.x * 64;
  int lane = t & 63;
  int wu = __builtin_amdgcn_readfirstlane(t >> 6);
  int lm = lane & 15, quad = lane >> 4;
  int wmr = (wu & 1) * 32, wn = (wu >> 1) * 64;
  int rb = wu * 32, rr = lane >> 3, phys = lane & 7;
  int am = t >> 3, akc = t & 7;  // A-conversion element: row am, k-chunk akc

  auto STAGEB = [&](int bufsel, int k0) {
    char* base = sm + 16384 + bufsel * 65536;
#pragma unroll
    for (int p = 0; p < 4; ++p) {
      int row = rb + p * 8 + rr;
      int kc = (phys - row) & 7;  // global-side swizzle -> LDS [row][(kc+row)&7]
      gl16(whb + (size_t)row * 1024 + k0 + kc * 8, base + (rb + p * 8) * 128);
      gl16(wmb + (size_t)row * 1024 + k0 + kc * 8, base + 32768 + (rb + p * 8) * 128);
    }
  };

  float4 xf0, xf1;
  auto LOADX = [&](int k0) {
    const float* ap = x + (size_t)(m0 + am) * 1024 + k0 + akc * 8;
    xf0 = *reinterpret_cast<const float4*>(ap);
    xf1 = *reinterpret_cast<const float4*>(ap + 4);
  };

  // prologue: B(0) FIRST, then x(0) — convert's implicit wait on x (youngest)
  // also drains B(0).
  STAGEB(0, 0);
  LOADX(0);

  float4v zero = {0.f, 0.f, 0.f, 0.f};
  float4v acc[2][4];
#pragma unroll
  for (int i = 0; i < 2; ++i)
#pragma unroll
    for (int j = 0; j < 4; ++j) acc[i][j] = zero;

#pragma unroll 1
  for (int kt = 0; kt < 16; ++kt) {
    int k0 = kt * 64;
    // convert current x regs -> hi/lo (compiler inserts the vmcnt wait here,
    // which also drains this wave's B(t) DMAs — they are older than x(t))
    short8 hi, lo;
    {
      float vv[8] = {xf0.x, xf0.y, xf0.z, xf0.w, xf1.x, xf1.y, xf1.z, xf1.w};
#pragma unroll
      for (int e = 0; e < 8; ++e) {
        short h = bf16s(vv[e]);
        hi[e] = h;
        lo[e] = bf16s(vv[e] - b2f(h));
      }
    }
    asm volatile("" ::: "memory");
    __builtin_amdgcn_s_barrier();  // all waves done reading A(t-1) LDS + drained own B(t)
    asm volatile("" ::: "memory");
    *reinterpret_cast<short8*>(sm + am * 128 + ((akc + am) & 7) * 16) = hi;
    *reinterpret_cast<short8*>(sm + 8192 + am * 128 + ((akc + am) & 7) * 16) = lo;
    *reinterpret_cast<short8*>(xb + (size_t)(m0 + am) * 1024 + k0 + akc * 8) = hi;  // xcvt fold
    if (kt < 15) {
      STAGEB((kt + 1) & 1, k0 + 64);  // B prefetch -> other buffer
      LOADX(k0 + 64);                 // x prefetch -> regs
    }
    asm volatile("s_waitcnt lgkmcnt(0)" ::: "memory");   // A ds_writes visible
    __builtin_amdgcn_s_barrier();
    asm volatile("" ::: "memory");

    const char* bb = sm + 16384 + (kt & 1) * 65536;
#pragma unroll
    for (int kh = 0; kh < 2; ++kh) {
      short8 ah[2], al[2], bh[4], bm[4];
#pragma unroll
      for (int i = 0; i < 2; ++i) {
        int row = wmr + i * 16 + lm;
        int ph = ((kh * 4 + quad) + row) & 7;
        ah[i] = *reinterpret_cast<const short8*>(sm + row * 128 + ph * 16);
        al[i] = *reinterpret_cast<const short8*>(sm + 8192 + row * 128 + ph * 16);
      }
#pragma unroll
      for (int j = 0; j < 4; ++j) {
        int rn = wn + j * 16 + lm;
        int ph = ((kh * 4 + quad) + rn) & 7;
        bh[j] = *reinterpret_cast<const short8*>(bb + rn * 128 + ph * 16);
        bm[j] = *reinterpret_cast<const short8*>(bb + 32768 + rn * 128 + ph * 16);
      }
#pragma unroll
      for (int i = 0; i < 2; ++i)
#pragma unroll
        for (int j = 0; j < 4; ++j) {
          acc[i][j] = MFMA16(ah[i], bh[j], acc[i][j]);
          acc[i][j] = MFMA16(ah[i], bm[j], acc[i][j]);
          acc[i][j] = MFMA16(al[i], bh[j], acc[i][j]);
        }
    }
  }

  // ---- fused bucket epilogue (n0 = 0; block covers all 32 groups) ----
  int b = m0 >> 12;
  int l0 = m0 & 4095;
  int kk = lm & 7;
#pragma unroll
  for (int j = 0; j < 4; ++j) {
    int n = wn + j * 16 + lm;             // this lane's column (0..255)
    int g = n >> 3;                        // group 0..31
    int side = g >> 4, h = g & 15;
    int slab = (side * 4 + b) * 16 + h;
    float bias = (float)bsc[n];
    float pp = 0.f;
#pragma unroll
    for (int i = 0; i < 2; ++i)
#pragma unroll
      for (int r = 0; r < 4; ++r) {
        float v = acc[i][j][r] + bias;
        // 8-lane argmax, first-max (lowest kk) tie-break
        float bmx = v; int bi = kk;
#pragma unroll
        for (int o = 1; o < 8; o <<= 1) {
          float vo = __shfl_xor(bmx, o);
          int io = __shfl_xor(bi, o);
          if (vo > bmx || (vo == bmx && io < bi)) { bmx = vo; bi = io; }
        }
        // 2nd max (max over kk != argmax)
        float vm = (kk == bi) ? -3.0e38f : v;
#pragma unroll
        for (int o = 1; o < 8; o <<= 1) vm = fmaxf(vm, __shfl_xor(vm, o));
        // softmax prob for this lane's kk
        float e = __expf(v - bmx);
        float es = e;
#pragma unroll
        for (int o = 1; o < 8; o <<= 1) es += __shfl_xor(es, o);
        pp += e * (1.f / es);
        int l = l0 + wmr + i * 16 + quad * 4 + r;
        if (kk == 0) {
          bid[(slab << 12) | l] = bi;
          if (bmx - vm < 5e-4f) {
            int pos = atomicAdd(flagcnt, 1);
            if (pos < FLAGCAP) list[pos] = (slab << 12) | l;
          }
        }
      }
    // sum pp across the quad axis (32 rows handled by this wave) -> 1 atomic
    pp += __shfl_xor(pp, 16);
    pp += __shfl_xor(pp, 32);
    if (quad == 0) atomicAdd(&psumg[slab * 8 + kk], pp);
  }
}

// ---------------------------------------------------------------------------
// refine_kernel: exact fp64 scores for flagged tokens; overwrite bid.
// ---------------------------------------------------------------------------
__global__ __launch_bounds__(256) void refine_kernel(const float* __restrict__ x,
                                                     const double* __restrict__ wscg,
                                                     const double* __restrict__ bsc,
                                                     const int* __restrict__ flagcnt,
                                                     const int* __restrict__ list,
                                                     int* __restrict__ bid) {
  int lane = threadIdx.x & 63;
  int w = threadIdx.x >> 6;
  int cnt = flagcnt[0];
  if (cnt > FLAGCAP) cnt = FLAGCAP;
  for (int i = blockIdx.x * 4 + w; i < cnt; i += 1024) {
    int e = list[i];
    int slab = e >> 12, l = e & 4095;
    int side = slab >> 6, b = (slab >> 4) & 3, h = slab & 15;
    int g = side * 16 + h;
    int row = b * 4096 + l;
    double acc[8] = {0, 0, 0, 0, 0, 0, 0, 0};
    const float* xr = x + (size_t)row * 1024 + lane * 16;
    const double* wr = wscg + ((size_t)g * 1024 + lane * 16) * 8;
#pragma unroll
    for (int dd = 0; dd < 16; ++dd) {
      double xv = (double)xr[dd];
#pragma unroll
      for (int j = 0; j < 8; ++j) acc[j] += xv * wr[dd * 8 + j];
    }
#pragma unroll
    for (int j = 0; j < 8; ++j) {
      double v = acc[j];
      v += __shfl_xor(v, 32); v += __shfl_xor(v, 16); v += __shfl_xor(v, 8);
      v += __shfl_xor(v, 4);  v += __shfl_xor(v, 2);  v += __shfl_xor(v, 1);
      acc[j] = v + bsc[g * 8 + j];
    }
    if (lane == 0) {
      double mx = acc[0]; int am = 0;
#pragma unroll
      for (int j = 1; j < 8; ++j) { if (acc[j] > mx) { mx = acc[j]; am = j; } }
      bid[(slab << 12) | l] = am;
    }
  }
}

// ---------------------------------------------------------------------------
// sort_kernel: stable counting sort into 8 buckets per (side,b,h)
// ---------------------------------------------------------------------------
__global__ __launch_bounds__(256) void sort_kernel(const int* __restrict__ bid,
                                                   int* __restrict__ sortq,
                                                   int* __restrict__ sortk,
                                                   int* __restrict__ cntg) {
  int blk = blockIdx.x;
  int side = blk >> 6, b = (blk >> 4) & 3, h = blk & 15;
  const int* ids = bid + (((side * 4 + b) * 16 + h) << 12);
  int* outp = (side ? sortk : sortq) + ((b * 16 + h) << 12);
  __shared__ int cnt[8][257];
  __shared__ int base[8];
  int t = threadIdx.x;
  int loc[16];
  int hist[8] = {0, 0, 0, 0, 0, 0, 0, 0};
#pragma unroll
  for (int j = 0; j < 16; ++j) { loc[j] = ids[t * 16 + j] & 7; hist[loc[j]]++; }
#pragma unroll
  for (int k = 0; k < 8; ++k) cnt[k][t + 1] = hist[k];
  if (t < 8) cnt[t][0] = 0;
  __syncthreads();
  if (t < 8) {
    for (int i = 1; i <= 256; ++i) cnt[t][i] += cnt[t][i - 1];
  }
  __syncthreads();
  if (t == 0) {
    int run = 0;
    for (int k = 0; k < 8; ++k) { base[k] = run; run += cnt[k][256]; }
  }
  if (t < 8) cntg[((side * 4 + b) * 16 + h) * 8 + t] = cnt[t][256];
  __syncthreads();
#pragma unroll
  for (int j = 0; j < 16; ++j) {
    int k = loc[j];
    int before = 0;
#pragma unroll
    for (int i = 0; i < 16; ++i) before += (i < j && loc[i] == k) ? 1 : 0;
    int pos = base[k] + cnt[k][t] + before;
    outp[pos] = t * 16 + j;
  }
}

// ---------------------------------------------------------------------------
// gemm256: C[M,N] = A[M,1024](bf16) * Bt[N,1024]^T (+bias). 256x256 tile,
// BK=64, 512 thr (8 waves, 2x4 per 128x128 quadrant as 64x32 strips).
// R4 version (best measured: ~104us, MfmaUtil 42%): R1 4-phase schedule with
// counted vmcnt(4) + XCD-chunked blockIdx swizzle (FETCH 151->94MB).
// ---------------------------------------------------------------------------
template <bool CBF16>
__global__ __launch_bounds__(512, 2) void gemm256(const __hip_bfloat16* __restrict__ A,
                                                  const __hip_bfloat16* __restrict__ Bt,
                                                  void* __restrict__ Cv,
                                                  const float* __restrict__ b0,
                                                  const float* __restrict__ b1,
                                                  const float* __restrict__ b2,
                                                  int nblk, int cpx) {
  __shared__ char sm[131072];  // buf0: A 32K | B 32K ; buf1: A 32K | B 32K
  int t = threadIdx.x;
  // XCD-aware swizzle: consecutive-per-XCD chunks (cpx = nwg/8)
  int blk = (blockIdx.x & 7) * cpx + (blockIdx.x >> 3);
  int m0 = (blk / nblk) * 256;
  int n0 = (blk % nblk) * 256;
  int lane = t & 63;
  int wu = __builtin_amdgcn_readfirstlane(t >> 6);
  int lm = lane & 15, quad = lane >> 4;
  int rr = lane >> 3, phys = lane & 7;
  int wrow = (wu & 1) * 64;   // m-offset of wave strip within quadrant
  int wcol = (wu >> 1) * 32;  // n-offset of wave strip within quadrant

  constexpr int QM[4] = {0, 0, 1, 1};
  constexpr int QN[4] = {0, 1, 1, 0};

  // stage one half-tile of the NEXT K-tile into buffer bufn.
  // j: 0 = A-half0, 1 = B-half0, 2 = B-half1, 3 = A-half1
  auto STAGE = [&](char* bufn, int j, int kS) {
    const int mat = (j == 1 || j == 2) ? 1 : 0;
    const int hm = (j >= 2) ? 1 : 0;
    const __hip_bfloat16* src = mat ? Bt : A;
    int gb = mat ? n0 : m0;
    char* lb = bufn + mat * 32768 + hm * 16384;
#pragma unroll
    for (int i = 0; i < 2; ++i) {
      int r = hm * 128 + (wu * 2 + i) * 8 + rr;
      int kc = (phys - r) & 7;  // global-side swizzle -> LDS [r][(kc+r)&7]
      gl16(src + (size_t)(gb + r) * 1024 + kS + kc * 8, lb + (wu * 2 + i) * 1024);
    }
  };

  // prologue: stage tile 0 (all 4 halves, steady-state order) into buf0
#pragma unroll
  for (int j = 0; j < 4; ++j) STAGE(sm, j, 0);

  float4v zero = {0.f, 0.f, 0.f, 0.f};
  float4v acc[4][4][2];
#pragma unroll
  for (int q = 0; q < 4; ++q)
#pragma unroll
    for (int mi = 0; mi < 4; ++mi)
#pragma unroll
      for (int ni = 0; ni < 2; ++ni) acc[q][mi][ni] = zero;

  short8 a[4][2], b[2][2];
  auto READA = [&](const char* bc, int qm) {
#pragma unroll
    for (int mi = 0; mi < 4; ++mi) {
      int row = qm * 128 + wrow + mi * 16 + lm;
#pragma unroll
      for (int ks = 0; ks < 2; ++ks) {
        int ph = ((ks * 4 + quad) + row) & 7;
        a[mi][ks] = *reinterpret_cast<const short8*>(bc + row * 128 + ph * 16);
      }
    }
  };
  auto READB = [&](const char* bc, int qn) {
#pragma unroll
    for (int ni = 0; ni < 2; ++ni) {
      int rn = qn * 128 + wcol + ni * 16 + lm;
#pragma unroll
      for (int ks = 0; ks < 2; ++ks) {
        int ph = ((ks * 4 + quad) + rn) & 7;
        b[ni][ks] = *reinterpret_cast<const short8*>(bc + 32768 + rn * 128 + ph * 16);
      }
    }
  };

#pragma unroll 1
  for (int kt = 0; kt < 16; ++kt) {
    char* bc = sm + ((kt & 1) << 16);
    char* bn = sm + (((kt & 1) ^ 1) << 16);
    int kS = (kt < 15) ? (kt + 1) * 64 : 960;  // clamp: last tile re-stages k=960 (harmless)
#pragma unroll
    for (int j = 0; j < 4; ++j) {
      if (j < 3) {
        asm volatile("s_waitcnt vmcnt(4)" ::: "memory");
        __builtin_amdgcn_s_barrier();
      }
      if (j == 0) { READA(bc, 0); READB(bc, 0); }
      else if (j == 1) { READB(bc, 1); }
      else if (j == 2) { READA(bc, 1); }
      else { READB(bc, 0); }
      STAGE(bn, j, kS);
      __builtin_amdgcn_s_setprio(1);
#pragma unroll
      for (int mi = 0; mi < 4; ++mi)
#pragma unroll
        for (int ni = 0; ni < 2; ++ni)
#pragma unroll
          for (int ks = 0; ks < 2; ++ks)
            acc[j][mi][ni] = MFMA16(a[mi][ks], b[ni][ks], acc[j][mi][ni]);
      __builtin_amdgcn_s_setprio(0);
    }
  }
  // drain trailing stage DMAs before LDS deallocation / epilogue
  asm volatile("s_waitcnt vmcnt(0)" ::: "memory");

  if constexpr (CBF16) {
#pragma unroll
    for (int j = 0; j < 4; ++j)
#pragma unroll
      for (int mi = 0; mi < 4; ++mi)
#pragma unroll
        for (int ni = 0; ni < 2; ++ni) {
          int nn = n0 + QN[j] * 128 + wcol + ni * 16 + lm;
          int s = nn >> 10, nnb = nn & 1023;
          const float* bias = (s == 0) ? b0 : (s == 1) ? b1 : b2;
          float bvx = bias[nnb];
          __hip_bfloat16* C = (__hip_bfloat16*)Cv + (size_t)s * BL * 1024;
#pragma unroll
          for (int r = 0; r < 4; ++r) {
            int row = m0 + QM[j] * 128 + wrow + mi * 16 + quad * 4 + r;
            C[(size_t)row * 1024 + nnb] = __float2bfloat16(acc[j][mi][ni][r] + bvx);
          }
        }
  } else {
    float* C = (float*)Cv;
#pragma unroll
    for (int j = 0; j < 4; ++j)
#pragma unroll
      for (int mi = 0; mi < 4; ++mi)
#pragma unroll
        for (int ni = 0; ni < 2; ++ni) {
          int nn = n0 + QN[j] * 128 + wcol + ni * 16 + lm;
          float bvx = b0[nn];
#pragma unroll
          for (int r = 0; r < 4; ++r) {
            int row = m0 + QM[j] * 128 + wrow + mi * 16 + quad * 4 + r;
            C[(size_t)row * 1024 + nn] = acc[j][mi][ni][r] + bvx;
          }
        }
  }
}

// ---------------------------------------------------------------------------
// vt_kernel: gather sorted V and transpose -> vT[cid][dim][key]
// ---------------------------------------------------------------------------
__global__ __launch_bounds__(256) void vt_kernel(const __hip_bfloat16* __restrict__ vb,
                                                 const int* __restrict__ sortk,
                                                 __hip_bfloat16* __restrict__ vT) {
  int cid = blockIdx.x;
  int b = cid >> 7, h = (cid >> 3) & 15, n = cid & 7;
  int sbase = ((b * 16 + h) << 12) + n * 512;
  __shared__ __hip_bfloat16 ls[64][72];
  int t = threadIdx.x;
  for (int kt = 0; kt < 8; ++kt) {
    __syncthreads();
#pragma unroll
    for (int p = 0; p < 2; ++p) {
      int sid = p * 256 + t;
      int key = sid >> 3, kc = sid & 7;
      int tok = sortk[sbase + kt * 64 + key];
      short8 v = *reinterpret_cast<const short8*>(vb + ((size_t)(b * 4096 + tok) * 16 + h) * 64 + kc * 8);
      *reinterpret_cast<short8*>(&ls[key][kc * 8]) = v;
    }
    __syncthreads();
#pragma unroll
    for (int p = 0; p < 2; ++p) {
      int sid = p * 256 + t;
      int dim = sid >> 3, kc = sid & 7;
      short8 o;
#pragma unroll
      for (int j = 0; j < 8; ++j) o[j] = *reinterpret_cast<short*>(&ls[kc * 8 + j][dim]);
      *reinterpret_cast<short8*>(vT + ((size_t)cid * 64 + dim) * 512 + kt * 64 + kc * 8) = o;
    }
  }
}

// ---------------------------------------------------------------------------
// attn_kernel v2: ONE block per chunk (512 blocks, 512 thr = 8 waves).
// Stage whole 512-key K + V^T into LDS once; 4 q-rounds x 8 k-tiles of pure
// LDS+MFMA with zero barriers after the stage barrier. (unchanged from R8)
// ---------------------------------------------------------------------------
__global__ __launch_bounds__(512, 2) void attn_kernel(const __hip_bfloat16* __restrict__ qb,
                                                      const __hip_bfloat16* __restrict__ kb,
                                                      const __hip_bfloat16* __restrict__ vT,
                                                      const int* __restrict__ sortq,
                                                      const int* __restrict__ sortk,
                                                      __hip_bfloat16* __restrict__ ao) {
  __shared__ char sm[149504];
  int t = threadIdx.x;
  int lane = t & 63, w = t >> 6;  // w 0..7
  int lm = lane & 15, quad = lane >> 4;
  int cid = blockIdx.x;
  int b = cid >> 7, h = (cid >> 3) & 15, n = cid & 7;
  int sbase = (b * 16 + h) << 12;
  int psOff = 131072 + w * 2304;

  // ---- stage whole chunk: K tiles [kt][row][chunk-swz], V^T tiles same ----
  {
    int row = t >> 3, kc = t & 7;  // 512 thr = 64 rows x 8 chunks
    int sw = ((kc + row) & 7) * 16;
#pragma unroll
    for (int kt = 0; kt < 8; ++kt) {
      int tok = sortk[sbase + n * 512 + kt * 64 + row];
      short8 kv = *reinterpret_cast<const short8*>(
          kb + ((size_t)(b * 4096 + tok) * 16 + h) * 64 + kc * 8);
      *reinterpret_cast<short8*>(sm + kt * 8192 + row * 128 + sw) = kv;
      short8 vv = *reinterpret_cast<const short8*>(
          vT + ((size_t)cid * 64 + row) * 512 + kt * 64 + kc * 8);
      *reinterpret_cast<short8*>(sm + 65536 + kt * 8192 + row * 128 + sw) = vv;
    }
  }
  __syncthreads();

  float4v zero = {0.f, 0.f, 0.f, 0.f};
#pragma unroll 1
  for (int qr = 0; qr < 4; ++qr) {
    int qtok = sortq[sbase + n * 512 + qr * 128 + w * 16 + lm];
    const __hip_bfloat16* qp = qb + ((size_t)(b * 4096 + qtok) * 16 + h) * 64 + quad * 8;
    short8 aq0 = *reinterpret_cast<const short8*>(qp);
    short8 aq1 = *reinterpret_cast<const short8*>(qp + 32);

    float4v accO[4];
#pragma unroll
    for (int i = 0; i < 4; ++i) accO[i] = zero;
    float lsum[4] = {0.f, 0.f, 0.f, 0.f};

#pragma unroll 1
    for (int kt = 0; kt < 8; ++kt) {
      const char* Kt = sm + kt * 8192;
      const char* Vt = sm + 65536 + kt * 8192;
#pragma unroll
      for (int nt = 0; nt < 4; ++nt) {
        int key = nt * 16 + lm;
        int ph0 = (quad + key) & 7;
        int ph1 = (4 + quad + key) & 7;
        short8 bk0 = *reinterpret_cast<const short8*>(Kt + key * 128 + ph0 * 16);
        short8 bk1 = *reinterpret_cast<const short8*>(Kt + key * 128 + ph1 * 16);
        float4v S = zero;
        S = MFMA16(aq0, bk0, S);
        S = MFMA16(aq1, bk1, S);
#pragma unroll
        for (int r = 0; r < 4; ++r) {
          float e = __expf(S[r] * 0.125f);
          lsum[r] += e;
          *reinterpret_cast<short*>(sm + psOff + (quad * 4 + r) * 144 + key * 2) = bf16s(e);
        }
      }
      __builtin_amdgcn_s_waitcnt(0);  // P writes visible before P reads (same wave)
#pragma unroll
      for (int ks = 0; ks < 2; ++ks) {
        short8 ap = *reinterpret_cast<const short8*>(sm + psOff + lm * 144 + ks * 64 + quad * 16);
#pragma unroll
        for (int dt = 0; dt < 4; ++dt) {
          int dim = dt * 16 + lm;
          int ph = (ks * 4 + quad + dim) & 7;
          short8 bv = *reinterpret_cast<const short8*>(Vt + dim * 128 + ph * 16);
          accO[dt] = MFMA16(ap, bv, accO[dt]);
        }
      }
    }
#pragma unroll
    for (int r = 0; r < 4; ++r) {
      float l = lsum[r];
      l += __shfl_xor(l, 1); l += __shfl_xor(l, 2);
      l += __shfl_xor(l, 4); l += __shfl_xor(l, 8);
      lsum[r] = 1.f / l;
    }
    // transpose O through the P region for coalesced stores (wave-local)
#pragma unroll
    for (int dt = 0; dt < 4; ++dt)
#pragma unroll
      for (int r = 0; r < 4; ++r)
        *reinterpret_cast<short*>(sm + psOff + (quad * 4 + r) * 144 + (dt * 16 + lm) * 2) =
            bf16s(accO[dt][r] * lsum[r]);
    __builtin_amdgcn_s_waitcnt(0);
    int q2 = lane >> 2, c = lane & 3;
    int tok2 = sortq[sbase + n * 512 + qr * 128 + w * 16 + q2];
    __hip_bfloat16* op = ao + ((size_t)(b * 4096 + tok2) * 16 + h) * 64;
    short8 o0 = *reinterpret_cast<const short8*>(sm + psOff + q2 * 144 + c * 16);
    short8 o1 = *reinterpret_cast<const short8*>(sm + psOff + q2 * 144 + (c + 4) * 16);
    *reinterpret_cast<short8*>(op + c * 8) = o0;
    *reinterpret_cast<short8*>(op + (c + 4) * 8) = o1;
  }
}

// ---------------------------------------------------------------------------
// loss_kernel: extra_loss = (sum_q + sum_k)/16 over (cnt/L)*(psum/L)
// ---------------------------------------------------------------------------
__global__ __launch_bounds__(1024) void loss_kernel(const int* __restrict__ cntg,
                                                    const float* __restrict__ psumg,
                                                    float* __restrict__ out) {
  int t = threadIdx.x;
  float term = ((float)cntg[t] * (1.f / 4096.f)) * (psumg[t] * (1.f / 4096.f));
#pragma unroll
  for (int o = 1; o < 64; o <<= 1) term += __shfl_xor(term, o);
  __shared__ float wsum[16];
  if ((t & 63) == 0) wsum[t >> 6] = term;
  __syncthreads();
  if (t == 0) {
    float s = 0.f;
    for (int i = 0; i < 16; ++i) s += wsum[i];
    out[16777216] = s * (1.f / 16.f);
  }
}

// ---------------------------------------------------------------------------
extern "C" void kernel_launch(void* const* d_in, const int* in_sizes, int n_in,
                              void* d_out, int out_size, void* d_ws, size_t ws_size,
                              hipStream_t stream) {
  (void)in_sizes; (void)n_in; (void)out_size; (void)ws_size;
  const float* x   = (const float*)d_in[0];
  const float* wq  = (const float*)d_in[1];
  const float* bq  = (const float*)d_in[2];
  const float* wk  = (const float*)d_in[3];
  const float* bk  = (const float*)d_in[4];
  const float* wv  = (const float*)d_in[5];
  const float* bv  = (const float*)d_in[6];
  const float* wsh = (const float*)d_in[7];
  const float* wqs = (const float*)d_in[8];
  const float* wks = (const float*)d_in[9];
  const float* wo  = (const float*)d_in[10];
  const float* bo  = (const float*)d_in[11];

  char* ws = (char*)d_ws;
  __hip_bfloat16* wt_qkv = (__hip_bfloat16*)(ws + 0);            // 6291456
  __hip_bfloat16* wt_o   = (__hip_bfloat16*)(ws + 6291456);      // 2097152
  double* wscg  = (double*)(ws + 8388608);                       // 2097152
  double* bsc   = (double*)(ws + 10485760);                      // 2048
  __hip_bfloat16* qkv  = (__hip_bfloat16*)(ws + 10487808);       // 3*33554432 -> ends 111151104
  // overlaid inside qkv region (dead before gemm256<true> writes qkv):
  __hip_bfloat16* whb = (__hip_bfloat16*)(ws + 109051904);       // 524288
  __hip_bfloat16* wmb = (__hip_bfloat16*)(ws + 109576192);       // 524288
  int* flagcnt = (int*)(ws + 110100480);                         // 256
  int* list    = (int*)(ws + 110100736);                         // 524288
  __hip_bfloat16* attn = (__hip_bfloat16*)(ws + 111151104);      // 33554432
  int* bid    = (int*)(ws + 144705536);                          // 2097152
  int* sortq  = (int*)(ws + 146802688);                          // 1048576
  int* sortk  = (int*)(ws + 147851264);                          // 1048576
  float* psumg = (float*)(ws + 148899840);                       // 4096
  int* cntg    = (int*)(ws + 148903936);                         // 4096
  // d_out (67.1 MB): [0,33.5M) vT scratch; [33.5M,67.1M) xb scratch. Both dead
  // before gemm256<false> + loss write the real output.
  __hip_bfloat16* vT = (__hip_bfloat16*)d_out;
  __hip_bfloat16* xb = (__hip_bfloat16*)((char*)d_out + 33554432);
  float* out = (float*)d_out;

  hipMemsetAsync(psumg, 0, 8192, stream);
  hipMemsetAsync(flagcnt, 0, 4, stream);
  prep_wt<<<1024, 256, 0, stream>>>(wq, wk, wv, wo, wt_qkv, wt_o);
  prep_wsc<<<256, 256, 0, stream>>>(wq, wk, wsh, wqs, wks, bq, bk, wscg, bsc, whb, wmb);
  score_gemm<<<256, 512, 0, stream>>>(x, whb, wmb, bsc, xb, bid, psumg, flagcnt, list);
  refine_kernel<<<256, 256, 0, stream>>>(x, wscg, bsc, flagcnt, list, bid);
  sort_kernel<<<128, 256, 0, stream>>>(bid, sortq, sortk, cntg);
  gemm256<true><<<768, 512, 0, stream>>>(xb, wt_qkv, qkv, bq, bk, bv, 12, 96);
  vt_kernel<<<512, 256, 0, stream>>>(qkv + (size_t)2 * BL * 1024, sortk, vT);
  attn_kernel<<<512, 512, 0, stream>>>(qkv, qkv + (size_t)BL * 1024, vT, sortq, sortk, attn);
  gemm256<false><<<256, 512, 0, stream>>>(attn, wt_o, (void*)out, bo, bo, bo, 4, 32);
  loss_kernel<<<1, 1024, 0, stream>>>(cntg, psumg, out);
}

// Round 10
// 517.009 us; speedup vs baseline: 1.0183x; 1.0183x over previous
//
#include <hip/hip_runtime.h>
#include <hip/hip_bf16.h>

// dims
#define BB 4
#define LL 4096
#define DM 1024
#define HH 16
#define DHD 64
#define KB 8
#define BL 16384  // BB*LL
#define FLAGCAP 131072

typedef __attribute__((ext_vector_type(8))) short short8;
typedef __attribute__((ext_vector_type(4))) short short4v;
typedef __attribute__((ext_vector_type(4))) float float4v;

#define MFMA16(A, Bx, C) __builtin_amdgcn_mfma_f32_16x16x32_bf16(A, Bx, C, 0, 0, 0)

static __device__ __forceinline__ short bf16s(float f) {
  __hip_bfloat16 h = __float2bfloat16(f);
  return *reinterpret_cast<short*>(&h);
}
static __device__ __forceinline__ float b2f(short s) {
  __hip_bfloat16 h = *reinterpret_cast<__hip_bfloat16*>(&s);
  return __bfloat162float(h);
}
// async global->LDS DMA, 16B/lane; LDS dest = uniform base + lane*16
static __device__ __forceinline__ void gl16(const void* g, void* l) {
  __builtin_amdgcn_global_load_lds(
      (const __attribute__((address_space(1))) void*)g,
      (__attribute__((address_space(3))) void*)l, 16, 0, 0);
}

// ---------------------------------------------------------------------------
// xcvt2: x fp32 -> xh (bf16 hi, = xb for QKV gemm) + xl (bf16 residual).
// grid 8192 x 256.
// ---------------------------------------------------------------------------
__global__ __launch_bounds__(256) void xcvt2(const float* __restrict__ x,
                                             __hip_bfloat16* __restrict__ xh,
                                             __hip_bfloat16* __restrict__ xl) {
  int i = (blockIdx.x * 256 + threadIdx.x) * 8;
  float4 f0 = *reinterpret_cast<const float4*>(x + i);
  float4 f1 = *reinterpret_cast<const float4*>(x + i + 4);
  float vv[8] = {f0.x, f0.y, f0.z, f0.w, f1.x, f1.y, f1.z, f1.w};
  short8 hi, lo;
#pragma unroll
  for (int e = 0; e < 8; ++e) {
    short h = bf16s(vv[e]);
    hi[e] = h;
    lo[e] = bf16s(vv[e] - b2f(h));
  }
  *reinterpret_cast<short8*>(xh + i) = hi;
  *reinterpret_cast<short8*>(xl + i) = lo;
}

// ---------------------------------------------------------------------------
// prep_wt: transpose wq/wk/wv/wo ([k][n] fp32) -> [n][k] bf16
// ---------------------------------------------------------------------------
__global__ __launch_bounds__(256) void prep_wt(const float* __restrict__ wq,
                                               const float* __restrict__ wk,
                                               const float* __restrict__ wv,
                                               const float* __restrict__ wo,
                                               __hip_bfloat16* __restrict__ wt_qkv,
                                               __hip_bfloat16* __restrict__ wt_o) {
  int blk = blockIdx.x;
  int s = blk >> 8;
  int rem = blk & 255;
  int k0 = (rem >> 4) * 64;
  int n0 = (rem & 15) * 64;
  const float* src = (s == 0) ? wq : (s == 1) ? wk : (s == 2) ? wv : wo;
  __hip_bfloat16* dst = (s < 3) ? (wt_qkv + (size_t)s * 1024 * 1024) : wt_o;
  __shared__ float ls[64][65];
  int t = threadIdx.x;
#pragma unroll
  for (int p = 0; p < 4; ++p) {
    int sid = p * 256 + t;
    int r = sid >> 4, c4 = sid & 15;
    float4 v = *reinterpret_cast<const float4*>(src + (size_t)(k0 + r) * 1024 + n0 + c4 * 4);
    ls[r][c4 * 4 + 0] = v.x; ls[r][c4 * 4 + 1] = v.y;
    ls[r][c4 * 4 + 2] = v.z; ls[r][c4 * 4 + 3] = v.w;
  }
  __syncthreads();
#pragma unroll
  for (int p = 0; p < 4; ++p) {
    int sid = p * 256 + t;
    int n = sid >> 4, kq = sid & 15;
    short4v pk;
#pragma unroll
    for (int j = 0; j < 4; ++j) pk[j] = bf16s(ls[kq * 4 + j][n]);
    *reinterpret_cast<short4v*>(dst + (size_t)(n0 + n) * 1024 + k0 + kq * 4) = pk;
  }
}

// ---------------------------------------------------------------------------
// prep_wsc: fused score weights. wscg[g][d][kk] fp64, bsc[col] fp64,
// whb/wmb [col][d] bf16 hi/mid split. grid 256, 256 thr.
// ---------------------------------------------------------------------------
__global__ __launch_bounds__(256) void prep_wsc(const float* __restrict__ wq,
                                                const float* __restrict__ wk,
                                                const float* __restrict__ wsh,
                                                const float* __restrict__ wqs,
                                                const float* __restrict__ wks,
                                                const float* __restrict__ bq,
                                                const float* __restrict__ bk,
                                                double* __restrict__ wscg,
                                                double* __restrict__ bsc,
                                                __hip_bfloat16* __restrict__ whb,
                                                __hip_bfloat16* __restrict__ wmb) {
  int col = blockIdx.x;
  int side = col >> 7, h = (col >> 3) & 15, kk = col & 7;
  int g = side * 16 + h;
  const float* w = side ? wk : wq;
  const float* wscore = side ? wks : wqs;
  __shared__ double mix[64];
  int t = threadIdx.x;
  if (t < 64)
    mix[t] = 0.9 * (double)wsh[(h * 64 + t) * 8 + kk] +
             0.1 * (double)wscore[(h * 64 + t) * 8 + kk];
  __syncthreads();
#pragma unroll
  for (int p = 0; p < 4; ++p) {
    int d = p * 256 + t;
    double acc = 0.0;
    const float* wr = w + (size_t)d * 1024 + h * 64;
#pragma unroll
    for (int j = 0; j < 64; ++j) acc += (double)wr[j] * mix[j];
    wscg[((size_t)g * 1024 + d) * 8 + kk] = acc;
    short hi = bf16s((float)acc);
    short mid = bf16s((float)(acc - (double)b2f(hi)));
    *reinterpret_cast<short*>(whb + (size_t)col * 1024 + d) = hi;
    *reinterpret_cast<short*>(wmb + (size_t)col * 1024 + d) = mid;
  }
  if (t == 0) {
    const float* br = (side ? bk : bq) + h * 64;
    double acc = 0.0;
    for (int j = 0; j < 64; ++j) acc += (double)br[j] * mix[j];
    bsc[col] = acc;
  }
}

// ---------------------------------------------------------------------------
// score_gemm R10: pure gl16-staged GEMM, structural clone of gemm256 (the
// proven 42%-MfmaUtil template). S = xh*wh + xh*wm + xl*wh, all operands
// bf16 planes staged by global_load_lds. Tile 128x128, BK=64, 512 thr
// (8 waves as 2x4, 64x32 strips), grid 256 (1 round), LDS 131072 (= gemm256).
// 3 phases per K-step: hh, hm, lh (16 MFMA each). Stage units in consumption
// order {Ahi,Bwh,Bwm,Alo}; vmcnt(4)+barrier at each phase entry. Ledger
// (2 gl16/unit/thread): prologue out={Ahi,Bwh,Bwm,Alo}=8. ph0 wait(4)
// drains Ahi,Bwh; stages Ahi' (6). ph1 wait(4) drains Bwm (leaves Alo,Ahi');
// stages Bwh' (6). ph2 wait(4) drains Alo (leaves Ahi',Bwh'); stages
// Bwm',Alo' (8) -> steady state. No VALU convert / ds_write / lgkm in loop.
// Numerics: per-output accum order becomes hh0,hh1,hm0,hm1,lh0,lh1 (was
// interleaved) — ~1e-7 fp32 reordering, far below the 5e-4 tie threshold
// that routes ambiguous tokens to the fp64 refine path. Fused bucket
// epilogue remapped (128 rows x 16 groups per block, single writer/(slab,l)).
// ---------------------------------------------------------------------------
__global__ __launch_bounds__(512, 2) void score_gemm(const __hip_bfloat16* __restrict__ xh,
                                                     const __hip_bfloat16* __restrict__ xl,
                                                     const __hip_bfloat16* __restrict__ whb,
                                                     const __hip_bfloat16* __restrict__ wmb,
                                                     const double* __restrict__ bsc,
                                                     int* __restrict__ bid,
                                                     float* __restrict__ psumg,
                                                     int* __restrict__ flagcnt,
                                                     int* __restrict__ list) {
  __shared__ char sm[131072];  // 2 bufs x {Ahi 16K | Bwh 16K | Bwm 16K | Alo 16K}
  int t = threadIdx.x;
  int blk = (blockIdx.x & 7) * 32 + (blockIdx.x >> 3);  // XCD swizzle, 256%8==0
  int m0 = (blk >> 1) * 128;
  int n0 = (blk & 1) * 128;
  int lane = t & 63;
  int wu = __builtin_amdgcn_readfirstlane(t >> 6);
  int lm = lane & 15, quad = lane >> 4;
  int rr = lane >> 3, phys = lane & 7;
  int wrow = (wu & 1) * 64;   // m-offset of wave strip
  int wcol = (wu >> 1) * 32;  // n-offset of wave strip

  // stage unit u of K-step kS into buffer bufn. u: 0=Ahi,1=Bwh,2=Bwm,3=Alo
  auto STAGE = [&](char* bufn, int u, int kS) {
    const __hip_bfloat16* src = (u == 0) ? xh : (u == 1) ? whb : (u == 2) ? wmb : xl;
    int gb = (u == 1 || u == 2) ? n0 : m0;
    char* lb = bufn + u * 16384;
#pragma unroll
    for (int i = 0; i < 2; ++i) {
      int r = (wu * 2 + i) * 8 + rr;
      int kc = (phys - r) & 7;  // global-side swizzle -> LDS [r][(kc+r)&7]
      gl16(src + (size_t)(gb + r) * 1024 + kS + kc * 8, lb + (wu * 2 + i) * 1024);
    }
  };

  // prologue: stage tile 0 in consumption order
  STAGE(sm, 0, 0); STAGE(sm, 1, 0); STAGE(sm, 2, 0); STAGE(sm, 3, 0);

  float4v zero = {0.f, 0.f, 0.f, 0.f};
  float4v acc[4][2];
#pragma unroll
  for (int mi = 0; mi < 4; ++mi)
#pragma unroll
    for (int ni = 0; ni < 2; ++ni) acc[mi][ni] = zero;

  short8 ahi[4][2], alo[4][2], bwh[2][2], bwm[2][2];
  auto READA = [&](short8 (&aa)[4][2], const char* base) {
#pragma unroll
    for (int mi = 0; mi < 4; ++mi) {
      int row = wrow + mi * 16 + lm;
#pragma unroll
      for (int ks = 0; ks < 2; ++ks) {
        int ph = ((ks * 4 + quad) + row) & 7;
        aa[mi][ks] = *reinterpret_cast<const short8*>(base + row * 128 + ph * 16);
      }
    }
  };
  auto READB = [&](short8 (&bb)[2][2], const char* base) {
#pragma unroll
    for (int ni = 0; ni < 2; ++ni) {
      int rn = wcol + ni * 16 + lm;
#pragma unroll
      for (int ks = 0; ks < 2; ++ks) {
        int ph = ((ks * 4 + quad) + rn) & 7;
        bb[ni][ks] = *reinterpret_cast<const short8*>(base + rn * 128 + ph * 16);
      }
    }
  };

#define SMFMA(AA, BB)                                                        \
  __builtin_amdgcn_s_setprio(1);                                             \
  _Pragma("unroll") for (int mi = 0; mi < 4; ++mi)                           \
      _Pragma("unroll") for (int ni = 0; ni < 2; ++ni)                       \
          _Pragma("unroll") for (int ks = 0; ks < 2; ++ks)                   \
              acc[mi][ni] = MFMA16(AA[mi][ks], BB[ni][ks], acc[mi][ni]);     \
  __builtin_amdgcn_s_setprio(0);

#pragma unroll 1
  for (int kt = 0; kt < 16; ++kt) {
    char* bc = sm + ((kt & 1) << 16);
    char* bn = sm + (((kt & 1) ^ 1) << 16);
    int kS = (kt < 15) ? (kt + 1) * 64 : 960;  // clamp: last tile re-stages (harmless)

    // ph0: hh — reads Ahi, Bwh
    asm volatile("s_waitcnt vmcnt(4)" ::: "memory");
    __builtin_amdgcn_s_barrier();
    READA(ahi, bc);
    READB(bwh, bc + 16384);
    STAGE(bn, 0, kS);
    SMFMA(ahi, bwh)

    // ph1: hm — reads Bwm (Ahi resident)
    asm volatile("s_waitcnt vmcnt(4)" ::: "memory");
    __builtin_amdgcn_s_barrier();
    READB(bwm, bc + 32768);
    STAGE(bn, 1, kS);
    SMFMA(ahi, bwm)

    // ph2: lh — reads Alo (Bwh resident)
    asm volatile("s_waitcnt vmcnt(4)" ::: "memory");
    __builtin_amdgcn_s_barrier();
    READA(alo, bc + 49152);
    STAGE(bn, 2, kS);
    STAGE(bn, 3, kS);
    SMFMA(alo, bwh)
  }
  asm volatile("s_waitcnt vmcnt(0)" ::: "memory");
#undef SMFMA

  // ---- fused bucket epilogue ----
  int b = m0 >> 12;
  int l0 = m0 & 4095;
  int kk = lm & 7;
#pragma unroll
  for (int ni = 0; ni < 2; ++ni) {
    int n = n0 + wcol + ni * 16 + lm;      // this lane's column (0..255)
    int g = n >> 3;                         // group 0..31
    int side = g >> 4, h = g & 15;
    int slab = (side * 4 + b) * 16 + h;
    float bias = (float)bsc[n];
    float pp = 0.f;
#pragma unroll
    for (int mi = 0; mi < 4; ++mi)
#pragma unroll
      for (int r = 0; r < 4; ++r) {
        float v = acc[mi][ni][r] + bias;
        // 8-lane argmax, first-max (lowest kk) tie-break
        float bmx = v; int bi = kk;
#pragma unroll
        for (int o = 1; o < 8; o <<= 1) {
          float vo = __shfl_xor(bmx, o);
          int io = __shfl_xor(bi, o);
          if (vo > bmx || (vo == bmx && io < bi)) { bmx = vo; bi = io; }
        }
        // 2nd max (max over kk != argmax)
        float vm = (kk == bi) ? -3.0e38f : v;
#pragma unroll
        for (int o = 1; o < 8; o <<= 1) vm = fmaxf(vm, __shfl_xor(vm, o));
        // softmax prob for this lane's kk
        float e = __expf(v - bmx);
        float es = e;
#pragma unroll
        for (int o = 1; o < 8; o <<= 1) es += __shfl_xor(es, o);
        pp += e * (1.f / es);
        int l = l0 + wrow + mi * 16 + quad * 4 + r;
        if (kk == 0) {
          bid[(slab << 12) | l] = bi;
          if (bmx - vm < 5e-4f) {
            int pos = atomicAdd(flagcnt, 1);
            if (pos < FLAGCAP) list[pos] = (slab << 12) | l;
          }
        }
      }
    // sum pp across quads (64 rows handled by this wave) -> 1 atomic
    pp += __shfl_xor(pp, 16);
    pp += __shfl_xor(pp, 32);
    if (quad == 0) atomicAdd(&psumg[slab * 8 + kk], pp);
  }
}

// ---------------------------------------------------------------------------
// refine_kernel: exact fp64 scores for flagged tokens; overwrite bid.
// ---------------------------------------------------------------------------
__global__ __launch_bounds__(256) void refine_kernel(const float* __restrict__ x,
                                                     const double* __restrict__ wscg,
                                                     const double* __restrict__ bsc,
                                                     const int* __restrict__ flagcnt,
                                                     const int* __restrict__ list,
                                                     int* __restrict__ bid) {
  int lane = threadIdx.x & 63;
  int w = threadIdx.x >> 6;
  int cnt = flagcnt[0];
  if (cnt > FLAGCAP) cnt = FLAGCAP;
  for (int i = blockIdx.x * 4 + w; i < cnt; i += 1024) {
    int e = list[i];
    int slab = e >> 12, l = e & 4095;
    int side = slab >> 6, b = (slab >> 4) & 3, h = slab & 15;
    int g = side * 16 + h;
    int row = b * 4096 + l;
    double acc[8] = {0, 0, 0, 0, 0, 0, 0, 0};
    const float* xr = x + (size_t)row * 1024 + lane * 16;
    const double* wr = wscg + ((size_t)g * 1024 + lane * 16) * 8;
#pragma unroll
    for (int dd = 0; dd < 16; ++dd) {
      double xv = (double)xr[dd];
#pragma unroll
      for (int j = 0; j < 8; ++j) acc[j] += xv * wr[dd * 8 + j];
    }
#pragma unroll
    for (int j = 0; j < 8; ++j) {
      double v = acc[j];
      v += __shfl_xor(v, 32); v += __shfl_xor(v, 16); v += __shfl_xor(v, 8);
      v += __shfl_xor(v, 4);  v += __shfl_xor(v, 2);  v += __shfl_xor(v, 1);
      acc[j] = v + bsc[g * 8 + j];
    }
    if (lane == 0) {
      double mx = acc[0]; int am = 0;
#pragma unroll
      for (int j = 1; j < 8; ++j) { if (acc[j] > mx) { mx = acc[j]; am = j; } }
      bid[(slab << 12) | l] = am;
    }
  }
}

// ---------------------------------------------------------------------------
// sort_kernel: stable counting sort into 8 buckets per (side,b,h)
// ---------------------------------------------------------------------------
__global__ __launch_bounds__(256) void sort_kernel(const int* __restrict__ bid,
                                                   int* __restrict__ sortq,
                                                   int* __restrict__ sortk,
                                                   int* __restrict__ cntg) {
  int blk = blockIdx.x;
  int side = blk >> 6, b = (blk >> 4) & 3, h = blk & 15;
  const int* ids = bid + (((side * 4 + b) * 16 + h) << 12);
  int* outp = (side ? sortk : sortq) + ((b * 16 + h) << 12);
  __shared__ int cnt[8][257];
  __shared__ int base[8];
  int t = threadIdx.x;
  int loc[16];
  int hist[8] = {0, 0, 0, 0, 0, 0, 0, 0};
#pragma unroll
  for (int j = 0; j < 16; ++j) { loc[j] = ids[t * 16 + j] & 7; hist[loc[j]]++; }
#pragma unroll
  for (int k = 0; k < 8; ++k) cnt[k][t + 1] = hist[k];
  if (t < 8) cnt[t][0] = 0;
  __syncthreads();
  if (t < 8) {
    for (int i = 1; i <= 256; ++i) cnt[t][i] += cnt[t][i - 1];
  }
  __syncthreads();
  if (t == 0) {
    int run = 0;
    for (int k = 0; k < 8; ++k) { base[k] = run; run += cnt[k][256]; }
  }
  if (t < 8) cntg[((side * 4 + b) * 16 + h) * 8 + t] = cnt[t][256];
  __syncthreads();
#pragma unroll
  for (int j = 0; j < 16; ++j) {
    int k = loc[j];
    int before = 0;
#pragma unroll
    for (int i = 0; i < 16; ++i) before += (i < j && loc[i] == k) ? 1 : 0;
    int pos = base[k] + cnt[k][t] + before;
    outp[pos] = t * 16 + j;
  }
}

// ---------------------------------------------------------------------------
// gemm256: C[M,N] = A[M,1024](bf16) * Bt[N,1024]^T (+bias). 256x256 tile,
// BK=64, 512 thr (8 waves, 2x4 per 128x128 quadrant as 64x32 strips).
// R4 version (best measured: ~104us, MfmaUtil 42%): R1 4-phase schedule with
// counted vmcnt(4) + XCD-chunked blockIdx swizzle (FETCH 151->94MB).
// ---------------------------------------------------------------------------
template <bool CBF16>
__global__ __launch_bounds__(512, 2) void gemm256(const __hip_bfloat16* __restrict__ A,
                                                  const __hip_bfloat16* __restrict__ Bt,
                                                  void* __restrict__ Cv,
                                                  const float* __restrict__ b0,
                                                  const float* __restrict__ b1,
                                                  const float* __restrict__ b2,
                                                  int nblk, int cpx) {
  __shared__ char sm[131072];  // buf0: A 32K | B 32K ; buf1: A 32K | B 32K
  int t = threadIdx.x;
  // XCD-aware swizzle: consecutive-per-XCD chunks (cpx = nwg/8)
  int blk = (blockIdx.x & 7) * cpx + (blockIdx.x >> 3);
  int m0 = (blk / nblk) * 256;
  int n0 = (blk % nblk) * 256;
  int lane = t & 63;
  int wu = __builtin_amdgcn_readfirstlane(t >> 6);
  int lm = lane & 15, quad = lane >> 4;
  int rr = lane >> 3, phys = lane & 7;
  int wrow = (wu & 1) * 64;   // m-offset of wave strip within quadrant
  int wcol = (wu >> 1) * 32;  // n-offset of wave strip within quadrant

  constexpr int QM[4] = {0, 0, 1, 1};
  constexpr int QN[4] = {0, 1, 1, 0};

  // stage one half-tile of the NEXT K-tile into buffer bufn.
  // j: 0 = A-half0, 1 = B-half0, 2 = B-half1, 3 = A-half1
  auto STAGE = [&](char* bufn, int j, int kS) {
    const int mat = (j == 1 || j == 2) ? 1 : 0;
    const int hm = (j >= 2) ? 1 : 0;
    const __hip_bfloat16* src = mat ? Bt : A;
    int gb = mat ? n0 : m0;
    char* lb = bufn + mat * 32768 + hm * 16384;
#pragma unroll
    for (int i = 0; i < 2; ++i) {
      int r = hm * 128 + (wu * 2 + i) * 8 + rr;
      int kc = (phys - r) & 7;  // global-side swizzle -> LDS [r][(kc+r)&7]
      gl16(src + (size_t)(gb + r) * 1024 + kS + kc * 8, lb + (wu * 2 + i) * 1024);
    }
  };

  // prologue: stage tile 0 (all 4 halves, steady-state order) into buf0
#pragma unroll
  for (int j = 0; j < 4; ++j) STAGE(sm, j, 0);

  float4v zero = {0.f, 0.f, 0.f, 0.f};
  float4v acc[4][4][2];
#pragma unroll
  for (int q = 0; q < 4; ++q)
#pragma unroll
    for (int mi = 0; mi < 4; ++mi)
#pragma unroll
      for (int ni = 0; ni < 2; ++ni) acc[q][mi][ni] = zero;

  short8 a[4][2], b[2][2];
  auto READA = [&](const char* bc, int qm) {
#pragma unroll
    for (int mi = 0; mi < 4; ++mi) {
      int row = qm * 128 + wrow + mi * 16 + lm;
#pragma unroll
      for (int ks = 0; ks < 2; ++ks) {
        int ph = ((ks * 4 + quad) + row) & 7;
        a[mi][ks] = *reinterpret_cast<const short8*>(bc + row * 128 + ph * 16);
      }
    }
  };
  auto READB = [&](const char* bc, int qn) {
#pragma unroll
    for (int ni = 0; ni < 2; ++ni) {
      int rn = qn * 128 + wcol + ni * 16 + lm;
#pragma unroll
      for (int ks = 0; ks < 2; ++ks) {
        int ph = ((ks * 4 + quad) + rn) & 7;
        b[ni][ks] = *reinterpret_cast<const short8*>(bc + 32768 + rn * 128 + ph * 16);
      }
    }
  };

#pragma unroll 1
  for (int kt = 0; kt < 16; ++kt) {
    char* bc = sm + ((kt & 1) << 16);
    char* bn = sm + (((kt & 1) ^ 1) << 16);
    int kS = (kt < 15) ? (kt + 1) * 64 : 960;  // clamp: last tile re-stages k=960 (harmless)
#pragma unroll
    for (int j = 0; j < 4; ++j) {
      if (j < 3) {
        asm volatile("s_waitcnt vmcnt(4)" ::: "memory");
        __builtin_amdgcn_s_barrier();
      }
      if (j == 0) { READA(bc, 0); READB(bc, 0); }
      else if (j == 1) { READB(bc, 1); }
      else if (j == 2) { READA(bc, 1); }
      else { READB(bc, 0); }
      STAGE(bn, j, kS);
      __builtin_amdgcn_s_setprio(1);
#pragma unroll
      for (int mi = 0; mi < 4; ++mi)
#pragma unroll
        for (int ni = 0; ni < 2; ++ni)
#pragma unroll
          for (int ks = 0; ks < 2; ++ks)
            acc[j][mi][ni] = MFMA16(a[mi][ks], b[ni][ks], acc[j][mi][ni]);
      __builtin_amdgcn_s_setprio(0);
    }
  }
  // drain trailing stage DMAs before LDS deallocation / epilogue
  asm volatile("s_waitcnt vmcnt(0)" ::: "memory");

  if constexpr (CBF16) {
#pragma unroll
    for (int j = 0; j < 4; ++j)
#pragma unroll
      for (int mi = 0; mi < 4; ++mi)
#pragma unroll
        for (int ni = 0; ni < 2; ++ni) {
          int nn = n0 + QN[j] * 128 + wcol + ni * 16 + lm;
          int s = nn >> 10, nnb = nn & 1023;
          const float* bias = (s == 0) ? b0 : (s == 1) ? b1 : b2;
          float bvx = bias[nnb];
          __hip_bfloat16* C = (__hip_bfloat16*)Cv + (size_t)s * BL * 1024;
#pragma unroll
          for (int r = 0; r < 4; ++r) {
            int row = m0 + QM[j] * 128 + wrow + mi * 16 + quad * 4 + r;
            C[(size_t)row * 1024 + nnb] = __float2bfloat16(acc[j][mi][ni][r] + bvx);
          }
        }
  } else {
    float* C = (float*)Cv;
#pragma unroll
    for (int j = 0; j < 4; ++j)
#pragma unroll
      for (int mi = 0; mi < 4; ++mi)
#pragma unroll
        for (int ni = 0; ni < 2; ++ni) {
          int nn = n0 + QN[j] * 128 + wcol + ni * 16 + lm;
          float bvx = b0[nn];
#pragma unroll
          for (int r = 0; r < 4; ++r) {
            int row = m0 + QM[j] * 128 + wrow + mi * 16 + quad * 4 + r;
            C[(size_t)row * 1024 + nn] = acc[j][mi][ni][r] + bvx;
          }
        }
  }
}

// ---------------------------------------------------------------------------
// vt_kernel: gather sorted V and transpose -> vT[cid][dim][key]
// ---------------------------------------------------------------------------
__global__ __launch_bounds__(256) void vt_kernel(const __hip_bfloat16* __restrict__ vb,
                                                 const int* __restrict__ sortk,
                                                 __hip_bfloat16* __restrict__ vT) {
  int cid = blockIdx.x;
  int b = cid >> 7, h = (cid >> 3) & 15, n = cid & 7;
  int sbase = ((b * 16 + h) << 12) + n * 512;
  __shared__ __hip_bfloat16 ls[64][72];
  int t = threadIdx.x;
  for (int kt = 0; kt < 8; ++kt) {
    __syncthreads();
#pragma unroll
    for (int p = 0; p < 2; ++p) {
      int sid = p * 256 + t;
      int key = sid >> 3, kc = sid & 7;
      int tok = sortk[sbase + kt * 64 + key];
      short8 v = *reinterpret_cast<const short8*>(vb + ((size_t)(b * 4096 + tok) * 16 + h) * 64 + kc * 8);
      *reinterpret_cast<short8*>(&ls[key][kc * 8]) = v;
    }
    __syncthreads();
#pragma unroll
    for (int p = 0; p < 2; ++p) {
      int sid = p * 256 + t;
      int dim = sid >> 3, kc = sid & 7;
      short8 o;
#pragma unroll
      for (int j = 0; j < 8; ++j) o[j] = *reinterpret_cast<short*>(&ls[kc * 8 + j][dim]);
      *reinterpret_cast<short8*>(vT + ((size_t)cid * 64 + dim) * 512 + kt * 64 + kc * 8) = o;
    }
  }
}

// ---------------------------------------------------------------------------
// attn_kernel v2: ONE block per chunk (512 blocks, 512 thr = 8 waves).
// Stage whole 512-key K + V^T into LDS once; 4 q-rounds x 8 k-tiles of pure
// LDS+MFMA with zero barriers after the stage barrier. (unchanged from R8)
// ---------------------------------------------------------------------------
__global__ __launch_bounds__(512, 2) void attn_kernel(const __hip_bfloat16* __restrict__ qb,
                                                      const __hip_bfloat16* __restrict__ kb,
                                                      const __hip_bfloat16* __restrict__ vT,
                                                      const int* __restrict__ sortq,
                                                      const int* __restrict__ sortk,
                                                      __hip_bfloat16* __restrict__ ao) {
  __shared__ char sm[149504];
  int t = threadIdx.x;
  int lane = t & 63, w = t >> 6;  // w 0..7
  int lm = lane & 15, quad = lane >> 4;
  int cid = blockIdx.x;
  int b = cid >> 7, h = (cid >> 3) & 15, n = cid & 7;
  int sbase = (b * 16 + h) << 12;
  int psOff = 131072 + w * 2304;

  // ---- stage whole chunk: K tiles [kt][row][chunk-swz], V^T tiles same ----
  {
    int row = t >> 3, kc = t & 7;  // 512 thr = 64 rows x 8 chunks
    int sw = ((kc + row) & 7) * 16;
#pragma unroll
    for (int kt = 0; kt < 8; ++kt) {
      int tok = sortk[sbase + n * 512 + kt * 64 + row];
      short8 kv = *reinterpret_cast<const short8*>(
          kb + ((size_t)(b * 4096 + tok) * 16 + h) * 64 + kc * 8);
      *reinterpret_cast<short8*>(sm + kt * 8192 + row * 128 + sw) = kv;
      short8 vv = *reinterpret_cast<const short8*>(
          vT + ((size_t)cid * 64 + row) * 512 + kt * 64 + kc * 8);
      *reinterpret_cast<short8*>(sm + 65536 + kt * 8192 + row * 128 + sw) = vv;
    }
  }
  __syncthreads();

  float4v zero = {0.f, 0.f, 0.f, 0.f};
#pragma unroll 1
  for (int qr = 0; qr < 4; ++qr) {
    int qtok = sortq[sbase + n * 512 + qr * 128 + w * 16 + lm];
    const __hip_bfloat16* qp = qb + ((size_t)(b * 4096 + qtok) * 16 + h) * 64 + quad * 8;
    short8 aq0 = *reinterpret_cast<const short8*>(qp);
    short8 aq1 = *reinterpret_cast<const short8*>(qp + 32);

    float4v accO[4];
#pragma unroll
    for (int i = 0; i < 4; ++i) accO[i] = zero;
    float lsum[4] = {0.f, 0.f, 0.f, 0.f};

#pragma unroll 1
    for (int kt = 0; kt < 8; ++kt) {
      const char* Kt = sm + kt * 8192;
      const char* Vt = sm + 65536 + kt * 8192;
#pragma unroll
      for (int nt = 0; nt < 4; ++nt) {
        int key = nt * 16 + lm;
        int ph0 = (quad + key) & 7;
        int ph1 = (4 + quad + key) & 7;
        short8 bk0 = *reinterpret_cast<const short8*>(Kt + key * 128 + ph0 * 16);
        short8 bk1 = *reinterpret_cast<const short8*>(Kt + key * 128 + ph1 * 16);
        float4v S = zero;
        S = MFMA16(aq0, bk0, S);
        S = MFMA16(aq1, bk1, S);
#pragma unroll
        for (int r = 0; r < 4; ++r) {
          float e = __expf(S[r] * 0.125f);
          lsum[r] += e;
          *reinterpret_cast<short*>(sm + psOff + (quad * 4 + r) * 144 + key * 2) = bf16s(e);
        }
      }
      __builtin_amdgcn_s_waitcnt(0);  // P writes visible before P reads (same wave)
#pragma unroll
      for (int ks = 0; ks < 2; ++ks) {
        short8 ap = *reinterpret_cast<const short8*>(sm + psOff + lm * 144 + ks * 64 + quad * 16);
#pragma unroll
        for (int dt = 0; dt < 4; ++dt) {
          int dim = dt * 16 + lm;
          int ph = (ks * 4 + quad + dim) & 7;
          short8 bv = *reinterpret_cast<const short8*>(Vt + dim * 128 + ph * 16);
          accO[dt] = MFMA16(ap, bv, accO[dt]);
        }
      }
    }
#pragma unroll
    for (int r = 0; r < 4; ++r) {
      float l = lsum[r];
      l += __shfl_xor(l, 1); l += __shfl_xor(l, 2);
      l += __shfl_xor(l, 4); l += __shfl_xor(l, 8);
      lsum[r] = 1.f / l;
    }
    // transpose O through the P region for coalesced stores (wave-local)
#pragma unroll
    for (int dt = 0; dt < 4; ++dt)
#pragma unroll
      for (int r = 0; r < 4; ++r)
        *reinterpret_cast<short*>(sm + psOff + (quad * 4 + r) * 144 + (dt * 16 + lm) * 2) =
            bf16s(accO[dt][r] * lsum[r]);
    __builtin_amdgcn_s_waitcnt(0);
    int q2 = lane >> 2, c = lane & 3;
    int tok2 = sortq[sbase + n * 512 + qr * 128 + w * 16 + q2];
    __hip_bfloat16* op = ao + ((size_t)(b * 4096 + tok2) * 16 + h) * 64;
    short8 o0 = *reinterpret_cast<const short8*>(sm + psOff + q2 * 144 + c * 16);
    short8 o1 = *reinterpret_cast<const short8*>(sm + psOff + q2 * 144 + (c + 4) * 16);
    *reinterpret_cast<short8*>(op + c * 8) = o0;
    *reinterpret_cast<short8*>(op + (c + 4) * 8) = o1;
  }
}

// ---------------------------------------------------------------------------
// loss_kernel: extra_loss = (sum_q + sum_k)/16 over (cnt/L)*(psum/L)
// ---------------------------------------------------------------------------
__global__ __launch_bounds__(1024) void loss_kernel(const int* __restrict__ cntg,
                                                    const float* __restrict__ psumg,
                                                    float* __restrict__ out) {
  int t = threadIdx.x;
  float term = ((float)cntg[t] * (1.f / 4096.f)) * (psumg[t] * (1.f / 4096.f));
#pragma unroll
  for (int o = 1; o < 64; o <<= 1) term += __shfl_xor(term, o);
  __shared__ float wsum[16];
  if ((t & 63) == 0) wsum[t >> 6] = term;
  __syncthreads();
  if (t == 0) {
    float s = 0.f;
    for (int i = 0; i < 16; ++i) s += wsum[i];
    out[16777216] = s * (1.f / 16.f);
  }
}

// ---------------------------------------------------------------------------
extern "C" void kernel_launch(void* const* d_in, const int* in_sizes, int n_in,
                              void* d_out, int out_size, void* d_ws, size_t ws_size,
                              hipStream_t stream) {
  (void)in_sizes; (void)n_in; (void)out_size; (void)ws_size;
  const float* x   = (const float*)d_in[0];
  const float* wq  = (const float*)d_in[1];
  const float* bq  = (const float*)d_in[2];
  const float* wk  = (const float*)d_in[3];
  const float* bk  = (const float*)d_in[4];
  const float* wv  = (const float*)d_in[5];
  const float* bv  = (const float*)d_in[6];
  const float* wsh = (const float*)d_in[7];
  const float* wqs = (const float*)d_in[8];
  const float* wks = (const float*)d_in[9];
  const float* wo  = (const float*)d_in[10];
  const float* bo  = (const float*)d_in[11];

  char* ws = (char*)d_ws;
  __hip_bfloat16* wt_qkv = (__hip_bfloat16*)(ws + 0);            // 6291456
  __hip_bfloat16* wt_o   = (__hip_bfloat16*)(ws + 6291456);      // 2097152
  double* wscg  = (double*)(ws + 8388608);                       // 2097152
  double* bsc   = (double*)(ws + 10485760);                      // 2048
  __hip_bfloat16* qkv  = (__hip_bfloat16*)(ws + 10487808);       // 3*33554432 -> ends 111151104
  // overlaid inside qkv region (dead before gemm256<true> writes qkv):
  __hip_bfloat16* whb = (__hip_bfloat16*)(ws + 109051904);       // 524288
  __hip_bfloat16* wmb = (__hip_bfloat16*)(ws + 109576192);       // 524288
  int* flagcnt = (int*)(ws + 110100480);                         // 256
  int* list    = (int*)(ws + 110100736);                         // 524288
  __hip_bfloat16* attn = (__hip_bfloat16*)(ws + 111151104);      // 33554432
  int* bid    = (int*)(ws + 144705536);                          // 2097152
  int* sortq  = (int*)(ws + 146802688);                          // 1048576
  int* sortk  = (int*)(ws + 147851264);                          // 1048576
  float* psumg = (float*)(ws + 148899840);                       // 4096
  int* cntg    = (int*)(ws + 148903936);                         // 4096
  // d_out (67.1 MB): [0,32M) xl scratch (dead before vt_kernel writes vT);
  // [0,33.5M) vT scratch; [33.5M,67.1M) xb=xh scratch. All dead before
  // gemm256<false> + loss write the real output.
  __hip_bfloat16* xl = (__hip_bfloat16*)d_out;
  __hip_bfloat16* vT = (__hip_bfloat16*)d_out;
  __hip_bfloat16* xb = (__hip_bfloat16*)((char*)d_out + 33554432);
  float* out = (float*)d_out;

  hipMemsetAsync(psumg, 0, 8192, stream);
  hipMemsetAsync(flagcnt, 0, 4, stream);
  prep_wt<<<1024, 256, 0, stream>>>(wq, wk, wv, wo, wt_qkv, wt_o);
  prep_wsc<<<256, 256, 0, stream>>>(wq, wk, wsh, wqs, wks, bq, bk, wscg, bsc, whb, wmb);
  xcvt2<<<8192, 256, 0, stream>>>(x, xb, xl);
  score_gemm<<<256, 512, 0, stream>>>(xb, xl, whb, wmb, bsc, bid, psumg, flagcnt, list);
  refine_kernel<<<256, 256, 0, stream>>>(x, wscg, bsc, flagcnt, list, bid);
  sort_kernel<<<128, 256, 0, stream>>>(bid, sortq, sortk, cntg);
  gemm256<true><<<768, 512, 0, stream>>>(xb, wt_qkv, qkv, bq, bk, bv, 12, 96);
  vt_kernel<<<512, 256, 0, stream>>>(qkv + (size_t)2 * BL * 1024, sortk, vT);
  attn_kernel<<<512, 512, 0, stream>>>(qkv, qkv + (size_t)BL * 1024, vT, sortq, sortk, attn);
  gemm256<false><<<256, 512, 0, stream>>>(attn, wt_o, (void*)out, bo, bo, bo, 4, 32);
  loss_kernel<<<1, 1024, 0, stream>>>(cntg, psumg, out);
}

// Round 11
// 503.740 us; speedup vs baseline: 1.0451x; 1.0263x over previous
//
#include <hip/hip_runtime.h>
#include <hip/hip_bf16.h>

// dims
#define BB 4
#define LL 4096
#define DM 1024
#define HH 16
#define DHD 64
#define KB 8
#define BL 16384  // BB*LL
#define FLAGCAP 131072

typedef __attribute__((ext_vector_type(8))) short short8;
typedef __attribute__((ext_vector_type(4))) short short4v;
typedef __attribute__((ext_vector_type(4))) float float4v;

#define MFMA16(A, Bx, C) __builtin_amdgcn_mfma_f32_16x16x32_bf16(A, Bx, C, 0, 0, 0)

static __device__ __forceinline__ short bf16s(float f) {
  __hip_bfloat16 h = __float2bfloat16(f);
  return *reinterpret_cast<short*>(&h);
}
static __device__ __forceinline__ float b2f(short s) {
  __hip_bfloat16 h = *reinterpret_cast<__hip_bfloat16*>(&s);
  return __bfloat162float(h);
}
// async global->LDS DMA, 16B/lane; LDS dest = uniform base + lane*16
static __device__ __forceinline__ void gl16(const void* g, void* l) {
  __builtin_amdgcn_global_load_lds(
      (const __attribute__((address_space(1))) void*)g,
      (__attribute__((address_space(3))) void*)l, 16, 0, 0);
}

// ---------------------------------------------------------------------------
// xcvt2: x fp32 -> xh (bf16 hi, = xb for QKV gemm) + xl (bf16 residual).
// grid 8192 x 256.
// ---------------------------------------------------------------------------
__global__ __launch_bounds__(256) void xcvt2(const float* __restrict__ x,
                                             __hip_bfloat16* __restrict__ xh,
                                             __hip_bfloat16* __restrict__ xl) {
  int i = (blockIdx.x * 256 + threadIdx.x) * 8;
  float4 f0 = *reinterpret_cast<const float4*>(x + i);
  float4 f1 = *reinterpret_cast<const float4*>(x + i + 4);
  float vv[8] = {f0.x, f0.y, f0.z, f0.w, f1.x, f1.y, f1.z, f1.w};
  short8 hi, lo;
#pragma unroll
  for (int e = 0; e < 8; ++e) {
    short h = bf16s(vv[e]);
    hi[e] = h;
    lo[e] = bf16s(vv[e] - b2f(h));
  }
  *reinterpret_cast<short8*>(xh + i) = hi;
  *reinterpret_cast<short8*>(xl + i) = lo;
}

// ---------------------------------------------------------------------------
// prep_wt: transpose wq/wk/wv/wo ([k][n] fp32) -> [n][k] bf16
// ---------------------------------------------------------------------------
__global__ __launch_bounds__(256) void prep_wt(const float* __restrict__ wq,
                                               const float* __restrict__ wk,
                                               const float* __restrict__ wv,
                                               const float* __restrict__ wo,
                                               __hip_bfloat16* __restrict__ wt_qkv,
                                               __hip_bfloat16* __restrict__ wt_o) {
  int blk = blockIdx.x;
  int s = blk >> 8;
  int rem = blk & 255;
  int k0 = (rem >> 4) * 64;
  int n0 = (rem & 15) * 64;
  const float* src = (s == 0) ? wq : (s == 1) ? wk : (s == 2) ? wv : wo;
  __hip_bfloat16* dst = (s < 3) ? (wt_qkv + (size_t)s * 1024 * 1024) : wt_o;
  __shared__ float ls[64][65];
  int t = threadIdx.x;
#pragma unroll
  for (int p = 0; p < 4; ++p) {
    int sid = p * 256 + t;
    int r = sid >> 4, c4 = sid & 15;
    float4 v = *reinterpret_cast<const float4*>(src + (size_t)(k0 + r) * 1024 + n0 + c4 * 4);
    ls[r][c4 * 4 + 0] = v.x; ls[r][c4 * 4 + 1] = v.y;
    ls[r][c4 * 4 + 2] = v.z; ls[r][c4 * 4 + 3] = v.w;
  }
  __syncthreads();
#pragma unroll
  for (int p = 0; p < 4; ++p) {
    int sid = p * 256 + t;
    int n = sid >> 4, kq = sid & 15;
    short4v pk;
#pragma unroll
    for (int j = 0; j < 4; ++j) pk[j] = bf16s(ls[kq * 4 + j][n]);
    *reinterpret_cast<short4v*>(dst + (size_t)(n0 + n) * 1024 + k0 + kq * 4) = pk;
  }
}

// ---------------------------------------------------------------------------
// prep_wsc: fused score weights. wscg[g][d][kk] fp64, bsc[col] fp64,
// whb/wmb [col][d] bf16 hi/mid split. grid 256, 256 thr.
// ---------------------------------------------------------------------------
__global__ __launch_bounds__(256) void prep_wsc(const float* __restrict__ wq,
                                                const float* __restrict__ wk,
                                                const float* __restrict__ wsh,
                                                const float* __restrict__ wqs,
                                                const float* __restrict__ wks,
                                                const float* __restrict__ bq,
                                                const float* __restrict__ bk,
                                                double* __restrict__ wscg,
                                                double* __restrict__ bsc,
                                                __hip_bfloat16* __restrict__ whb,
                                                __hip_bfloat16* __restrict__ wmb) {
  int col = blockIdx.x;
  int side = col >> 7, h = (col >> 3) & 15, kk = col & 7;
  int g = side * 16 + h;
  const float* w = side ? wk : wq;
  const float* wscore = side ? wks : wqs;
  __shared__ double mix[64];
  int t = threadIdx.x;
  if (t < 64)
    mix[t] = 0.9 * (double)wsh[(h * 64 + t) * 8 + kk] +
             0.1 * (double)wscore[(h * 64 + t) * 8 + kk];
  __syncthreads();
#pragma unroll
  for (int p = 0; p < 4; ++p) {
    int d = p * 256 + t;
    double acc = 0.0;
    const float* wr = w + (size_t)d * 1024 + h * 64;
#pragma unroll
    for (int j = 0; j < 64; ++j) acc += (double)wr[j] * mix[j];
    wscg[((size_t)g * 1024 + d) * 8 + kk] = acc;
    short hi = bf16s((float)acc);
    short mid = bf16s((float)(acc - (double)b2f(hi)));
    *reinterpret_cast<short*>(whb + (size_t)col * 1024 + d) = hi;
    *reinterpret_cast<short*>(wmb + (size_t)col * 1024 + d) = mid;
  }
  if (t == 0) {
    const float* br = (side ? bk : bq) + h * 64;
    double acc = 0.0;
    for (int j = 0; j < 64; ++j) acc += (double)br[j] * mix[j];
    bsc[col] = acc;
  }
}

// ---------------------------------------------------------------------------
// score_gemm R10: pure gl16-staged GEMM, structural clone of gemm256.
// S = xh*wh + xh*wm + xl*wh. Tile 128x128, BK=64, 512 thr, grid 256,
// LDS 131072. 3 phases/K-step (hh, hm, lh); stage units in consumption
// order {Ahi,Bwh,Bwm,Alo}; vmcnt(4)+barrier per phase entry. Fused bucket
// epilogue. (unchanged this round — R10 verified win)
// ---------------------------------------------------------------------------
__global__ __launch_bounds__(512, 2) void score_gemm(const __hip_bfloat16* __restrict__ xh,
                                                     const __hip_bfloat16* __restrict__ xl,
                                                     const __hip_bfloat16* __restrict__ whb,
                                                     const __hip_bfloat16* __restrict__ wmb,
                                                     const double* __restrict__ bsc,
                                                     int* __restrict__ bid,
                                                     float* __restrict__ psumg,
                                                     int* __restrict__ flagcnt,
                                                     int* __restrict__ list) {
  __shared__ char sm[131072];  // 2 bufs x {Ahi 16K | Bwh 16K | Bwm 16K | Alo 16K}
  int t = threadIdx.x;
  int blk = (blockIdx.x & 7) * 32 + (blockIdx.x >> 3);  // XCD swizzle, 256%8==0
  int m0 = (blk >> 1) * 128;
  int n0 = (blk & 1) * 128;
  int lane = t & 63;
  int wu = __builtin_amdgcn_readfirstlane(t >> 6);
  int lm = lane & 15, quad = lane >> 4;
  int rr = lane >> 3, phys = lane & 7;
  int wrow = (wu & 1) * 64;   // m-offset of wave strip
  int wcol = (wu >> 1) * 32;  // n-offset of wave strip

  // stage unit u of K-step kS into buffer bufn. u: 0=Ahi,1=Bwh,2=Bwm,3=Alo
  auto STAGE = [&](char* bufn, int u, int kS) {
    const __hip_bfloat16* src = (u == 0) ? xh : (u == 1) ? whb : (u == 2) ? wmb : xl;
    int gb = (u == 1 || u == 2) ? n0 : m0;
    char* lb = bufn + u * 16384;
#pragma unroll
    for (int i = 0; i < 2; ++i) {
      int r = (wu * 2 + i) * 8 + rr;
      int kc = (phys - r) & 7;  // global-side swizzle -> LDS [r][(kc+r)&7]
      gl16(src + (size_t)(gb + r) * 1024 + kS + kc * 8, lb + (wu * 2 + i) * 1024);
    }
  };

  // prologue: stage tile 0 in consumption order
  STAGE(sm, 0, 0); STAGE(sm, 1, 0); STAGE(sm, 2, 0); STAGE(sm, 3, 0);

  float4v zero = {0.f, 0.f, 0.f, 0.f};
  float4v acc[4][2];
#pragma unroll
  for (int mi = 0; mi < 4; ++mi)
#pragma unroll
    for (int ni = 0; ni < 2; ++ni) acc[mi][ni] = zero;

  short8 ahi[4][2], alo[4][2], bwh[2][2], bwm[2][2];
  auto READA = [&](short8 (&aa)[4][2], const char* base) {
#pragma unroll
    for (int mi = 0; mi < 4; ++mi) {
      int row = wrow + mi * 16 + lm;
#pragma unroll
      for (int ks = 0; ks < 2; ++ks) {
        int ph = ((ks * 4 + quad) + row) & 7;
        aa[mi][ks] = *reinterpret_cast<const short8*>(base + row * 128 + ph * 16);
      }
    }
  };
  auto READB = [&](short8 (&bb)[2][2], const char* base) {
#pragma unroll
    for (int ni = 0; ni < 2; ++ni) {
      int rn = wcol + ni * 16 + lm;
#pragma unroll
      for (int ks = 0; ks < 2; ++ks) {
        int ph = ((ks * 4 + quad) + rn) & 7;
        bb[ni][ks] = *reinterpret_cast<const short8*>(base + rn * 128 + ph * 16);
      }
    }
  };

#define SMFMA(AA, BB)                                                        \
  __builtin_amdgcn_s_setprio(1);                                             \
  _Pragma("unroll") for (int mi = 0; mi < 4; ++mi)                           \
      _Pragma("unroll") for (int ni = 0; ni < 2; ++ni)                       \
          _Pragma("unroll") for (int ks = 0; ks < 2; ++ks)                   \
              acc[mi][ni] = MFMA16(AA[mi][ks], BB[ni][ks], acc[mi][ni]);     \
  __builtin_amdgcn_s_setprio(0);

#pragma unroll 1
  for (int kt = 0; kt < 16; ++kt) {
    char* bc = sm + ((kt & 1) << 16);
    char* bn = sm + (((kt & 1) ^ 1) << 16);
    int kS = (kt < 15) ? (kt + 1) * 64 : 960;  // clamp: last tile re-stages (harmless)

    // ph0: hh — reads Ahi, Bwh
    asm volatile("s_waitcnt vmcnt(4)" ::: "memory");
    __builtin_amdgcn_s_barrier();
    READA(ahi, bc);
    READB(bwh, bc + 16384);
    STAGE(bn, 0, kS);
    SMFMA(ahi, bwh)

    // ph1: hm — reads Bwm (Ahi resident)
    asm volatile("s_waitcnt vmcnt(4)" ::: "memory");
    __builtin_amdgcn_s_barrier();
    READB(bwm, bc + 32768);
    STAGE(bn, 1, kS);
    SMFMA(ahi, bwm)

    // ph2: lh — reads Alo (Bwh resident)
    asm volatile("s_waitcnt vmcnt(4)" ::: "memory");
    __builtin_amdgcn_s_barrier();
    READA(alo, bc + 49152);
    STAGE(bn, 2, kS);
    STAGE(bn, 3, kS);
    SMFMA(alo, bwh)
  }
  asm volatile("s_waitcnt vmcnt(0)" ::: "memory");
#undef SMFMA

  // ---- fused bucket epilogue ----
  int b = m0 >> 12;
  int l0 = m0 & 4095;
  int kk = lm & 7;
#pragma unroll
  for (int ni = 0; ni < 2; ++ni) {
    int n = n0 + wcol + ni * 16 + lm;      // this lane's column (0..255)
    int g = n >> 3;                         // group 0..31
    int side = g >> 4, h = g & 15;
    int slab = (side * 4 + b) * 16 + h;
    float bias = (float)bsc[n];
    float pp = 0.f;
#pragma unroll
    for (int mi = 0; mi < 4; ++mi)
#pragma unroll
      for (int r = 0; r < 4; ++r) {
        float v = acc[mi][ni][r] + bias;
        // 8-lane argmax, first-max (lowest kk) tie-break
        float bmx = v; int bi = kk;
#pragma unroll
        for (int o = 1; o < 8; o <<= 1) {
          float vo = __shfl_xor(bmx, o);
          int io = __shfl_xor(bi, o);
          if (vo > bmx || (vo == bmx && io < bi)) { bmx = vo; bi = io; }
        }
        // 2nd max (max over kk != argmax)
        float vm = (kk == bi) ? -3.0e38f : v;
#pragma unroll
        for (int o = 1; o < 8; o <<= 1) vm = fmaxf(vm, __shfl_xor(vm, o));
        // softmax prob for this lane's kk
        float e = __expf(v - bmx);
        float es = e;
#pragma unroll
        for (int o = 1; o < 8; o <<= 1) es += __shfl_xor(es, o);
        pp += e * (1.f / es);
        int l = l0 + wrow + mi * 16 + quad * 4 + r;
        if (kk == 0) {
          bid[(slab << 12) | l] = bi;
          if (bmx - vm < 5e-4f) {
            int pos = atomicAdd(flagcnt, 1);
            if (pos < FLAGCAP) list[pos] = (slab << 12) | l;
          }
        }
      }
    // sum pp across quads (64 rows handled by this wave) -> 1 atomic
    pp += __shfl_xor(pp, 16);
    pp += __shfl_xor(pp, 32);
    if (quad == 0) atomicAdd(&psumg[slab * 8 + kk], pp);
  }
}

// ---------------------------------------------------------------------------
// refine_kernel: exact fp64 scores for flagged tokens; overwrite bid.
// ---------------------------------------------------------------------------
__global__ __launch_bounds__(256) void refine_kernel(const float* __restrict__ x,
                                                     const double* __restrict__ wscg,
                                                     const double* __restrict__ bsc,
                                                     const int* __restrict__ flagcnt,
                                                     const int* __restrict__ list,
                                                     int* __restrict__ bid) {
  int lane = threadIdx.x & 63;
  int w = threadIdx.x >> 6;
  int cnt = flagcnt[0];
  if (cnt > FLAGCAP) cnt = FLAGCAP;
  for (int i = blockIdx.x * 4 + w; i < cnt; i += 1024) {
    int e = list[i];
    int slab = e >> 12, l = e & 4095;
    int side = slab >> 6, b = (slab >> 4) & 3, h = slab & 15;
    int g = side * 16 + h;
    int row = b * 4096 + l;
    double acc[8] = {0, 0, 0, 0, 0, 0, 0, 0};
    const float* xr = x + (size_t)row * 1024 + lane * 16;
    const double* wr = wscg + ((size_t)g * 1024 + lane * 16) * 8;
#pragma unroll
    for (int dd = 0; dd < 16; ++dd) {
      double xv = (double)xr[dd];
#pragma unroll
      for (int j = 0; j < 8; ++j) acc[j] += xv * wr[dd * 8 + j];
    }
#pragma unroll
    for (int j = 0; j < 8; ++j) {
      double v = acc[j];
      v += __shfl_xor(v, 32); v += __shfl_xor(v, 16); v += __shfl_xor(v, 8);
      v += __shfl_xor(v, 4);  v += __shfl_xor(v, 2);  v += __shfl_xor(v, 1);
      acc[j] = v + bsc[g * 8 + j];
    }
    if (lane == 0) {
      double mx = acc[0]; int am = 0;
#pragma unroll
      for (int j = 1; j < 8; ++j) { if (acc[j] > mx) { mx = acc[j]; am = j; } }
      bid[(slab << 12) | l] = am;
    }
  }
}

// ---------------------------------------------------------------------------
// sort_kernel: stable counting sort into 8 buckets per (side,b,h)
// ---------------------------------------------------------------------------
__global__ __launch_bounds__(256) void sort_kernel(const int* __restrict__ bid,
                                                   int* __restrict__ sortq,
                                                   int* __restrict__ sortk,
                                                   int* __restrict__ cntg) {
  int blk = blockIdx.x;
  int side = blk >> 6, b = (blk >> 4) & 3, h = blk & 15;
  const int* ids = bid + (((side * 4 + b) * 16 + h) << 12);
  int* outp = (side ? sortk : sortq) + ((b * 16 + h) << 12);
  __shared__ int cnt[8][257];
  __shared__ int base[8];
  int t = threadIdx.x;
  int loc[16];
  int hist[8] = {0, 0, 0, 0, 0, 0, 0, 0};
#pragma unroll
  for (int j = 0; j < 16; ++j) { loc[j] = ids[t * 16 + j] & 7; hist[loc[j]]++; }
#pragma unroll
  for (int k = 0; k < 8; ++k) cnt[k][t + 1] = hist[k];
  if (t < 8) cnt[t][0] = 0;
  __syncthreads();
  if (t < 8) {
    for (int i = 1; i <= 256; ++i) cnt[t][i] += cnt[t][i - 1];
  }
  __syncthreads();
  if (t == 0) {
    int run = 0;
    for (int k = 0; k < 8; ++k) { base[k] = run; run += cnt[k][256]; }
  }
  if (t < 8) cntg[((side * 4 + b) * 16 + h) * 8 + t] = cnt[t][256];
  __syncthreads();
#pragma unroll
  for (int j = 0; j < 16; ++j) {
    int k = loc[j];
    int before = 0;
#pragma unroll
    for (int i = 0; i < 16; ++i) before += (i < j && loc[i] == k) ? 1 : 0;
    int pos = base[k] + cnt[k][t] + before;
    outp[pos] = t * 16 + j;
  }
}

// ---------------------------------------------------------------------------
// gemm256: C[M,N] = A[M,1024](bf16) * Bt[N,1024]^T (+bias). 256x256 tile,
// BK=64, 512 thr (8 waves, 2x4 per 128x128 quadrant as 64x32 strips).
// R4 version (best measured: ~104us, MfmaUtil 42% at nominal clock): R1
// 4-phase schedule with counted vmcnt(4) + XCD-chunked blockIdx swizzle.
// ---------------------------------------------------------------------------
template <bool CBF16>
__global__ __launch_bounds__(512, 2) void gemm256(const __hip_bfloat16* __restrict__ A,
                                                  const __hip_bfloat16* __restrict__ Bt,
                                                  void* __restrict__ Cv,
                                                  const float* __restrict__ b0,
                                                  const float* __restrict__ b1,
                                                  const float* __restrict__ b2,
                                                  int nblk, int cpx) {
  __shared__ char sm[131072];  // buf0: A 32K | B 32K ; buf1: A 32K | B 32K
  int t = threadIdx.x;
  // XCD-aware swizzle: consecutive-per-XCD chunks (cpx = nwg/8)
  int blk = (blockIdx.x & 7) * cpx + (blockIdx.x >> 3);
  int m0 = (blk / nblk) * 256;
  int n0 = (blk % nblk) * 256;
  int lane = t & 63;
  int wu = __builtin_amdgcn_readfirstlane(t >> 6);
  int lm = lane & 15, quad = lane >> 4;
  int rr = lane >> 3, phys = lane & 7;
  int wrow = (wu & 1) * 64;   // m-offset of wave strip within quadrant
  int wcol = (wu >> 1) * 32;  // n-offset of wave strip within quadrant

  constexpr int QM[4] = {0, 0, 1, 1};
  constexpr int QN[4] = {0, 1, 1, 0};

  // stage one half-tile of the NEXT K-tile into buffer bufn.
  // j: 0 = A-half0, 1 = B-half0, 2 = B-half1, 3 = A-half1
  auto STAGE = [&](char* bufn, int j, int kS) {
    const int mat = (j == 1 || j == 2) ? 1 : 0;
    const int hm = (j >= 2) ? 1 : 0;
    const __hip_bfloat16* src = mat ? Bt : A;
    int gb = mat ? n0 : m0;
    char* lb = bufn + mat * 32768 + hm * 16384;
#pragma unroll
    for (int i = 0; i < 2; ++i) {
      int r = hm * 128 + (wu * 2 + i) * 8 + rr;
      int kc = (phys - r) & 7;  // global-side swizzle -> LDS [r][(kc+r)&7]
      gl16(src + (size_t)(gb + r) * 1024 + kS + kc * 8, lb + (wu * 2 + i) * 1024);
    }
  };

  // prologue: stage tile 0 (all 4 halves, steady-state order) into buf0
#pragma unroll
  for (int j = 0; j < 4; ++j) STAGE(sm, j, 0);

  float4v zero = {0.f, 0.f, 0.f, 0.f};
  float4v acc[4][4][2];
#pragma unroll
  for (int q = 0; q < 4; ++q)
#pragma unroll
    for (int mi = 0; mi < 4; ++mi)
#pragma unroll
      for (int ni = 0; ni < 2; ++ni) acc[q][mi][ni] = zero;

  short8 a[4][2], b[2][2];
  auto READA = [&](const char* bc, int qm) {
#pragma unroll
    for (int mi = 0; mi < 4; ++mi) {
      int row = qm * 128 + wrow + mi * 16 + lm;
#pragma unroll
      for (int ks = 0; ks < 2; ++ks) {
        int ph = ((ks * 4 + quad) + row) & 7;
        a[mi][ks] = *reinterpret_cast<const short8*>(bc + row * 128 + ph * 16);
      }
    }
  };
  auto READB = [&](const char* bc, int qn) {
#pragma unroll
    for (int ni = 0; ni < 2; ++ni) {
      int rn = qn * 128 + wcol + ni * 16 + lm;
#pragma unroll
      for (int ks = 0; ks < 2; ++ks) {
        int ph = ((ks * 4 + quad) + rn) & 7;
        b[ni][ks] = *reinterpret_cast<const short8*>(bc + 32768 + rn * 128 + ph * 16);
      }
    }
  };

#pragma unroll 1
  for (int kt = 0; kt < 16; ++kt) {
    char* bc = sm + ((kt & 1) << 16);
    char* bn = sm + (((kt & 1) ^ 1) << 16);
    int kS = (kt < 15) ? (kt + 1) * 64 : 960;  // clamp: last tile re-stages k=960 (harmless)
#pragma unroll
    for (int j = 0; j < 4; ++j) {
      if (j < 3) {
        asm volatile("s_waitcnt vmcnt(4)" ::: "memory");
        __builtin_amdgcn_s_barrier();
      }
      if (j == 0) { READA(bc, 0); READB(bc, 0); }
      else if (j == 1) { READB(bc, 1); }
      else if (j == 2) { READA(bc, 1); }
      else { READB(bc, 0); }
      STAGE(bn, j, kS);
      __builtin_amdgcn_s_setprio(1);
#pragma unroll
      for (int mi = 0; mi < 4; ++mi)
#pragma unroll
        for (int ni = 0; ni < 2; ++ni)
#pragma unroll
          for (int ks = 0; ks < 2; ++ks)
            acc[j][mi][ni] = MFMA16(a[mi][ks], b[ni][ks], acc[j][mi][ni]);
      __builtin_amdgcn_s_setprio(0);
    }
  }
  // drain trailing stage DMAs before LDS deallocation / epilogue
  asm volatile("s_waitcnt vmcnt(0)" ::: "memory");

  if constexpr (CBF16) {
#pragma unroll
    for (int j = 0; j < 4; ++j)
#pragma unroll
      for (int mi = 0; mi < 4; ++mi)
#pragma unroll
        for (int ni = 0; ni < 2; ++ni) {
          int nn = n0 + QN[j] * 128 + wcol + ni * 16 + lm;
          int s = nn >> 10, nnb = nn & 1023;
          const float* bias = (s == 0) ? b0 : (s == 1) ? b1 : b2;
          float bvx = bias[nnb];
          __hip_bfloat16* C = (__hip_bfloat16*)Cv + (size_t)s * BL * 1024;
#pragma unroll
          for (int r = 0; r < 4; ++r) {
            int row = m0 + QM[j] * 128 + wrow + mi * 16 + quad * 4 + r;
            C[(size_t)row * 1024 + nnb] = __float2bfloat16(acc[j][mi][ni][r] + bvx);
          }
        }
  } else {
    float* C = (float*)Cv;
#pragma unroll
    for (int j = 0; j < 4; ++j)
#pragma unroll
      for (int mi = 0; mi < 4; ++mi)
#pragma unroll
        for (int ni = 0; ni < 2; ++ni) {
          int nn = n0 + QN[j] * 128 + wcol + ni * 16 + lm;
          float bvx = b0[nn];
#pragma unroll
          for (int r = 0; r < 4; ++r) {
            int row = m0 + QM[j] * 128 + wrow + mi * 16 + quad * 4 + r;
            C[(size_t)row * 1024 + nn] = acc[j][mi][ni][r] + bvx;
          }
        }
  }
}

// ---------------------------------------------------------------------------
// attn_kernel v3: ONE block per chunk (512 blocks, 512 thr = 8 waves).
// R11: vt_kernel FOLDED IN. Since R8, each vT panel had exactly one consumer
// (this block) — the HBM round-trip (32MB write + 32MB read) was pure waste.
// Staging now gathers V rows (same tokens as K) into a 64x144B LDS scratch
// and transposes tile-by-tile into the V^T region using vt_kernel's exact
// read/write pattern (same padding, same ((kc+dim)&7) swizzle) -> V^T bytes
// bit-identical to the vt_kernel path -> bit-identical output.
// LDS: K 64K @0 | V^T 64K @65536 | P 8x2304 @131072 | scratch 9216 @149504
//  = 158720 B (<= 160K, 1 block/CU). Compute phase unchanged from v2.
// ---------------------------------------------------------------------------
__global__ __launch_bounds__(512, 2) void attn_kernel(const __hip_bfloat16* __restrict__ qb,
                                                      const __hip_bfloat16* __restrict__ kb,
                                                      const __hip_bfloat16* __restrict__ vb,
                                                      const int* __restrict__ sortq,
                                                      const int* __restrict__ sortk,
                                                      __hip_bfloat16* __restrict__ ao) {
  __shared__ char sm[158720];
  int t = threadIdx.x;
  int lane = t & 63, w = t >> 6;  // w 0..7
  int lm = lane & 15, quad = lane >> 4;
  int cid = blockIdx.x;
  int b = cid >> 7, h = (cid >> 3) & 15, n = cid & 7;
  int sbase = (b * 16 + h) << 12;
  int psOff = 131072 + w * 2304;
  char* scr = sm + 149504;  // 64 rows x 144B ([key][72 shorts], vt-style pad)

  // ---- stage whole chunk: K gathered+swizzled; V gathered -> scratch ->
  //      transposed into V^T tiles (vt_kernel pattern, in-LDS) ----
  {
    int row = t >> 3, kc = t & 7;  // 512 thr = 64 rows x 8 chunks
    int sw = ((kc + row) & 7) * 16;
#pragma unroll 1
    for (int kt = 0; kt < 8; ++kt) {
      int tok = sortk[sbase + n * 512 + kt * 64 + row];
      const __hip_bfloat16* tp = kb + ((size_t)(b * 4096 + tok) * 16 + h) * 64 + kc * 8;
      short8 kv = *reinterpret_cast<const short8*>(tp);
      *reinterpret_cast<short8*>(sm + kt * 8192 + row * 128 + sw) = kv;
      // V row (same token) -> scratch row layout [key][dim]
      short8 vv = *reinterpret_cast<const short8*>(
          vb + ((size_t)(b * 4096 + tok) * 16 + h) * 64 + kc * 8);
      *reinterpret_cast<short8*>(scr + row * 144 + kc * 16) = vv;
      __syncthreads();
      // transpose scratch -> V^T tile: dim = row, key-chunk = kc
      short8 o;
#pragma unroll
      for (int j = 0; j < 8; ++j)
        o[j] = *reinterpret_cast<const short*>(scr + (kc * 8 + j) * 144 + row * 2);
      *reinterpret_cast<short8*>(sm + 65536 + kt * 8192 + row * 128 + sw) = o;
      __syncthreads();  // scratch reusable next kt; also publishes V^T tile
    }
  }
  __syncthreads();

  float4v zero = {0.f, 0.f, 0.f, 0.f};
#pragma unroll 1
  for (int qr = 0; qr < 4; ++qr) {
    int qtok = sortq[sbase + n * 512 + qr * 128 + w * 16 + lm];
    const __hip_bfloat16* qp = qb + ((size_t)(b * 4096 + qtok) * 16 + h) * 64 + quad * 8;
    short8 aq0 = *reinterpret_cast<const short8*>(qp);
    short8 aq1 = *reinterpret_cast<const short8*>(qp + 32);

    float4v accO[4];
#pragma unroll
    for (int i = 0; i < 4; ++i) accO[i] = zero;
    float lsum[4] = {0.f, 0.f, 0.f, 0.f};

#pragma unroll 1
    for (int kt = 0; kt < 8; ++kt) {
      const char* Kt = sm + kt * 8192;
      const char* Vt = sm + 65536 + kt * 8192;
#pragma unroll
      for (int nt = 0; nt < 4; ++nt) {
        int key = nt * 16 + lm;
        int ph0 = (quad + key) & 7;
        int ph1 = (4 + quad + key) & 7;
        short8 bk0 = *reinterpret_cast<const short8*>(Kt + key * 128 + ph0 * 16);
        short8 bk1 = *reinterpret_cast<const short8*>(Kt + key * 128 + ph1 * 16);
        float4v S = zero;
        S = MFMA16(aq0, bk0, S);
        S = MFMA16(aq1, bk1, S);
#pragma unroll
        for (int r = 0; r < 4; ++r) {
          float e = __expf(S[r] * 0.125f);
          lsum[r] += e;
          *reinterpret_cast<short*>(sm + psOff + (quad * 4 + r) * 144 + key * 2) = bf16s(e);
        }
      }
      __builtin_amdgcn_s_waitcnt(0);  // P writes visible before P reads (same wave)
#pragma unroll
      for (int ks = 0; ks < 2; ++ks) {
        short8 ap = *reinterpret_cast<const short8*>(sm + psOff + lm * 144 + ks * 64 + quad * 16);
#pragma unroll
        for (int dt = 0; dt < 4; ++dt) {
          int dim = dt * 16 + lm;
          int ph = (ks * 4 + quad + dim) & 7;
          short8 bv = *reinterpret_cast<const short8*>(Vt + dim * 128 + ph * 16);
          accO[dt] = MFMA16(ap, bv, accO[dt]);
        }
      }
    }
#pragma unroll
    for (int r = 0; r < 4; ++r) {
      float l = lsum[r];
      l += __shfl_xor(l, 1); l += __shfl_xor(l, 2);
      l += __shfl_xor(l, 4); l += __shfl_xor(l, 8);
      lsum[r] = 1.f / l;
    }
    // transpose O through the P region for coalesced stores (wave-local)
#pragma unroll
    for (int dt = 0; dt < 4; ++dt)
#pragma unroll
      for (int r = 0; r < 4; ++r)
        *reinterpret_cast<short*>(sm + psOff + (quad * 4 + r) * 144 + (dt * 16 + lm) * 2) =
            bf16s(accO[dt][r] * lsum[r]);
    __builtin_amdgcn_s_waitcnt(0);
    int q2 = lane >> 2, c = lane & 3;
    int tok2 = sortq[sbase + n * 512 + qr * 128 + w * 16 + q2];
    __hip_bfloat16* op = ao + ((size_t)(b * 4096 + tok2) * 16 + h) * 64;
    short8 o0 = *reinterpret_cast<const short8*>(sm + psOff + q2 * 144 + c * 16);
    short8 o1 = *reinterpret_cast<const short8*>(sm + psOff + q2 * 144 + (c + 4) * 16);
    *reinterpret_cast<short8*>(op + c * 8) = o0;
    *reinterpret_cast<short8*>(op + (c + 4) * 8) = o1;
  }
}

// ---------------------------------------------------------------------------
// loss_kernel: extra_loss = (sum_q + sum_k)/16 over (cnt/L)*(psum/L)
// ---------------------------------------------------------------------------
__global__ __launch_bounds__(1024) void loss_kernel(const int* __restrict__ cntg,
                                                    const float* __restrict__ psumg,
                                                    float* __restrict__ out) {
  int t = threadIdx.x;
  float term = ((float)cntg[t] * (1.f / 4096.f)) * (psumg[t] * (1.f / 4096.f));
#pragma unroll
  for (int o = 1; o < 64; o <<= 1) term += __shfl_xor(term, o);
  __shared__ float wsum[16];
  if ((t & 63) == 0) wsum[t >> 6] = term;
  __syncthreads();
  if (t == 0) {
    float s = 0.f;
    for (int i = 0; i < 16; ++i) s += wsum[i];
    out[16777216] = s * (1.f / 16.f);
  }
}

// ---------------------------------------------------------------------------
extern "C" void kernel_launch(void* const* d_in, const int* in_sizes, int n_in,
                              void* d_out, int out_size, void* d_ws, size_t ws_size,
                              hipStream_t stream) {
  (void)in_sizes; (void)n_in; (void)out_size; (void)ws_size;
  const float* x   = (const float*)d_in[0];
  const float* wq  = (const float*)d_in[1];
  const float* bq  = (const float*)d_in[2];
  const float* wk  = (const float*)d_in[3];
  const float* bk  = (const float*)d_in[4];
  const float* wv  = (const float*)d_in[5];
  const float* bv  = (const float*)d_in[6];
  const float* wsh = (const float*)d_in[7];
  const float* wqs = (const float*)d_in[8];
  const float* wks = (const float*)d_in[9];
  const float* wo  = (const float*)d_in[10];
  const float* bo  = (const float*)d_in[11];

  char* ws = (char*)d_ws;
  __hip_bfloat16* wt_qkv = (__hip_bfloat16*)(ws + 0);            // 6291456
  __hip_bfloat16* wt_o   = (__hip_bfloat16*)(ws + 6291456);      // 2097152
  double* wscg  = (double*)(ws + 8388608);                       // 2097152
  double* bsc   = (double*)(ws + 10485760);                      // 2048
  __hip_bfloat16* qkv  = (__hip_bfloat16*)(ws + 10487808);       // 3*33554432 -> ends 111151104
  // overlaid inside qkv region (dead before gemm256<true> writes qkv):
  __hip_bfloat16* whb = (__hip_bfloat16*)(ws + 109051904);       // 524288
  __hip_bfloat16* wmb = (__hip_bfloat16*)(ws + 109576192);       // 524288
  int* flagcnt = (int*)(ws + 110100480);                         // 256
  int* list    = (int*)(ws + 110100736);                         // 524288
  __hip_bfloat16* attn = (__hip_bfloat16*)(ws + 111151104);      // 33554432
  int* bid    = (int*)(ws + 144705536);                          // 2097152
  int* sortq  = (int*)(ws + 146802688);                          // 1048576
  int* sortk  = (int*)(ws + 147851264);                          // 1048576
  float* psumg = (float*)(ws + 148899840);                       // 4096
  int* cntg    = (int*)(ws + 148903936);                         // 4096
  // d_out (67.1 MB): [0,32M) xl scratch (dead after score_gemm);
  // [33.5M,67.1M) xb=xh scratch (dead after gemm256<true>). Both dead before
  // gemm256<false> + loss write the real output.
  __hip_bfloat16* xl = (__hip_bfloat16*)d_out;
  __hip_bfloat16* xb = (__hip_bfloat16*)((char*)d_out + 33554432);
  float* out = (float*)d_out;

  hipMemsetAsync(psumg, 0, 8192, stream);
  hipMemsetAsync(flagcnt, 0, 4, stream);
  prep_wt<<<1024, 256, 0, stream>>>(wq, wk, wv, wo, wt_qkv, wt_o);
  prep_wsc<<<256, 256, 0, stream>>>(wq, wk, wsh, wqs, wks, bq, bk, wscg, bsc, whb, wmb);
  xcvt2<<<8192, 256, 0, stream>>>(x, xb, xl);
  score_gemm<<<256, 512, 0, stream>>>(xb, xl, whb, wmb, bsc, bid, psumg, flagcnt, list);
  refine_kernel<<<256, 256, 0, stream>>>(x, wscg, bsc, flagcnt, list, bid);
  sort_kernel<<<128, 256, 0, stream>>>(bid, sortq, sortk, cntg);
  gemm256<true><<<768, 512, 0, stream>>>(xb, wt_qkv, qkv, bq, bk, bv, 12, 96);
  attn_kernel<<<512, 512, 0, stream>>>(qkv, qkv + (size_t)BL * 1024,
                                       qkv + (size_t)2 * BL * 1024, sortq, sortk, attn);
  gemm256<false><<<256, 512, 0, stream>>>(attn, wt_o, (void*)out, bo, bo, bo, 4, 32);
  loss_kernel<<<1, 1024, 0, stream>>>(cntg, psumg, out);
}